// Round 1
// baseline (1027.908 us; speedup 1.0000x reference)
//
#include <hip/hip_runtime.h>
#include <hip/hip_bf16.h>
#include <math.h>

// Shapes (fixed by the problem)
#define BB 512
#define NN 64
#define LL 64
#define DD 256
#define HH 256

__device__ __forceinline__ float sigmoidf_(float x) { return 1.0f / (1.0f + __expf(-x)); }

// ---------------------------------------------------------------------------
// K1: hidden[B*N, D] = emb[items]
// ---------------------------------------------------------------------------
__global__ __launch_bounds__(256) void gather_emb(
    const int* __restrict__ items, const float* __restrict__ emb,
    float* __restrict__ hidden)
{
    int i = blockIdx.x * 256 + threadIdx.x;   // over B*N*D/4 = 2,097,152 float4
    int row = i >> 6;                          // 64 float4 per row
    int c   = i & 63;
    int it  = items[row];
    ((float4*)hidden)[((size_t)row << 6) + c] = ((const float4*)emb)[((size_t)it << 6) + c];
}

// ---------------------------------------------------------------------------
// K2: hio[M,512] = hidden @ [W_ein | W_eout] + [b_ein | b_eout]
// 128x128 tile, 256 threads, 8x8 micro-tile, f32
// ---------------------------------------------------------------------------
__global__ __launch_bounds__(256) void gemm_hio(
    const float* __restrict__ h,
    const float* __restrict__ Wein, const float* __restrict__ bein,
    const float* __restrict__ Weout, const float* __restrict__ beout,
    float* __restrict__ hio)
{
    __shared__ float Xs[16][132];   // [k][m] (transposed)
    __shared__ float Ws[16][132];   // [k][n]
    const int tid = threadIdx.x;
    const int tx = tid & 15;
    const int ty = tid >> 4;
    const int bm = blockIdx.x * 128;
    const int bn = blockIdx.y * 128;        // 0,128,256,384
    const float* Wsrc = (bn < 256) ? Wein : Weout;
    const float* bsrc = (bn < 256) ? bein : beout;
    const int wn0 = (bn < 256) ? bn : bn - 256;

    float acc[8][8] = {};
    for (int k0 = 0; k0 < 256; k0 += 16) {
        #pragma unroll
        for (int it = 0; it < 2; ++it) {
            int s = tid + it * 256;          // 512 float4 slots
            int m = s >> 2;
            int kc = (s & 3) * 4;
            float4 v = *(const float4*)(h + (size_t)(bm + m) * 256 + k0 + kc);
            Xs[kc + 0][m] = v.x; Xs[kc + 1][m] = v.y; Xs[kc + 2][m] = v.z; Xs[kc + 3][m] = v.w;
        }
        #pragma unroll
        for (int it = 0; it < 2; ++it) {
            int s = tid + it * 256;
            int k = s >> 5;
            int c = (s & 31) * 4;
            float4 v = *(const float4*)(Wsrc + (size_t)(k0 + k) * 256 + wn0 + c);
            *(float4*)&Ws[k][c] = v;
        }
        __syncthreads();
        #pragma unroll
        for (int kk = 0; kk < 16; ++kk) {
            float a[8], b[8];
            *(float4*)&a[0] = *(const float4*)&Xs[kk][ty * 8];
            *(float4*)&a[4] = *(const float4*)&Xs[kk][ty * 8 + 4];
            *(float4*)&b[0] = *(const float4*)&Ws[kk][tx * 8];
            *(float4*)&b[4] = *(const float4*)&Ws[kk][tx * 8 + 4];
            #pragma unroll
            for (int i = 0; i < 8; i++)
                #pragma unroll
                for (int j = 0; j < 8; j++) acc[i][j] = fmaf(a[i], b[j], acc[i][j]);
        }
        __syncthreads();
    }
    float bb[8];
    #pragma unroll
    for (int j = 0; j < 8; j++) bb[j] = bsrc[wn0 + tx * 8 + j];
    #pragma unroll
    for (int i = 0; i < 8; i++) {
        int m = bm + ty * 8 + i;
        float4 o0 = make_float4(acc[i][0] + bb[0], acc[i][1] + bb[1], acc[i][2] + bb[2], acc[i][3] + bb[3]);
        float4 o1 = make_float4(acc[i][4] + bb[4], acc[i][5] + bb[5], acc[i][6] + bb[6], acc[i][7] + bb[7]);
        float* dst = hio + (size_t)m * 512 + bn + tx * 8;
        *(float4*)dst = o0;
        *(float4*)(dst + 4) = o1;
    }
}

// ---------------------------------------------------------------------------
// K3: inp[b, r, c0:c0+128] = A_half[b] @ hio_slab[b] + bias   (K=64 per batch)
// grid (512, 4); 64 rows x 128 cols per block, 4x8 micro-tile
// ---------------------------------------------------------------------------
__global__ __launch_bounds__(256) void adj_mm(
    const float* __restrict__ A,
    const float* __restrict__ hio,
    const float* __restrict__ biah, const float* __restrict__ boah,
    float* __restrict__ inp)
{
    const int b = blockIdx.x;
    const int slab = blockIdx.y;            // 0..3
    const int c0 = slab * 128;
    const int half = (c0 >= 256) ? 1 : 0;
    __shared__ float As[64][65];
    __shared__ float Hs[64][132];
    const int tid = threadIdx.x;
    const int tx = tid & 15, ty = tid >> 4;

    const float* Ab = A + (size_t)b * 8192 + half * 64;
    for (int s = tid; s < 1024; s += 256) {     // 64x64 floats
        int r = s >> 4;
        int c = (s & 15) * 4;
        float4 v = *(const float4*)(Ab + (size_t)r * 128 + c);
        As[r][c] = v.x; As[r][c + 1] = v.y; As[r][c + 2] = v.z; As[r][c + 3] = v.w;
    }
    const float* Hb = hio + (size_t)b * 64 * 512 + c0;
    for (int s = tid; s < 2048; s += 256) {     // 64x128 floats
        int k = s >> 5;
        int c = (s & 31) * 4;
        *(float4*)&Hs[k][c] = *(const float4*)(Hb + (size_t)k * 512 + c);
    }
    __syncthreads();
    float acc[4][8] = {};
    for (int kk = 0; kk < 64; ++kk) {
        float a[4], bf[8];
        #pragma unroll
        for (int i = 0; i < 4; i++) a[i] = As[ty + i * 16][kk];
        *(float4*)&bf[0] = *(const float4*)&Hs[kk][tx * 8];
        *(float4*)&bf[4] = *(const float4*)&Hs[kk][tx * 8 + 4];
        #pragma unroll
        for (int i = 0; i < 4; i++)
            #pragma unroll
            for (int j = 0; j < 8; j++) acc[i][j] = fmaf(a[i], bf[j], acc[i][j]);
    }
    const float* bias = half ? boah : biah;
    const int cb = c0 - half * 256;
    float bb[8];
    #pragma unroll
    for (int j = 0; j < 8; j++) bb[j] = bias[cb + tx * 8 + j];
    #pragma unroll
    for (int i = 0; i < 4; i++) {
        int r = ty + i * 16;
        float4 o0 = make_float4(acc[i][0] + bb[0], acc[i][1] + bb[1], acc[i][2] + bb[2], acc[i][3] + bb[3]);
        float4 o1 = make_float4(acc[i][4] + bb[4], acc[i][5] + bb[5], acc[i][6] + bb[6], acc[i][7] + bb[7]);
        float* dst = inp + ((size_t)b * 64 + r) * 512 + c0 + tx * 8;
        *(float4*)dst = o0;
        *(float4*)(dst + 4) = o1;
    }
}

// ---------------------------------------------------------------------------
// K4: GRU cell fused.  64x64 tile, 6 accumulator sets (r/i/n for gi and gh).
// gi over inp (K=512, W_i), gh over hidden (K=256, W_h), gates -> newh.
// ---------------------------------------------------------------------------
__global__ __launch_bounds__(256) void gru_fused(
    const float* __restrict__ inp, const float* __restrict__ hidden,
    const float* __restrict__ Wi, const float* __restrict__ bi,
    const float* __restrict__ Wh, const float* __restrict__ bh,
    float* __restrict__ newh)
{
    __shared__ float Xs[64][17];
    __shared__ float B0[16][68], B1[16][68], B2[16][68];
    const int tid = threadIdx.x;
    const int tx = tid & 15, ty = tid >> 4;
    const int bm = blockIdx.x * 64;
    const int bd = blockIdx.y * 64;

    float aR[4][4] = {}, aI[4][4] = {}, aN[4][4] = {};
    float hR[4][4] = {}, hI[4][4] = {}, hN[4][4] = {};

    // Phase 1: gi = inp @ W_i   (K = 512)
    for (int k0 = 0; k0 < 512; k0 += 16) {
        {
            int m = tid >> 2, kc = (tid & 3) * 4;
            float4 v = *(const float4*)(inp + (size_t)(bm + m) * 512 + k0 + kc);
            Xs[m][kc] = v.x; Xs[m][kc + 1] = v.y; Xs[m][kc + 2] = v.z; Xs[m][kc + 3] = v.w;
        }
        {
            int k = tid >> 4, c = (tid & 15) * 4;
            const float* wr = Wi + (size_t)(k0 + k) * 768 + bd + c;
            *(float4*)&B0[k][c] = *(const float4*)(wr);
            *(float4*)&B1[k][c] = *(const float4*)(wr + 256);
            *(float4*)&B2[k][c] = *(const float4*)(wr + 512);
        }
        __syncthreads();
        #pragma unroll
        for (int kk = 0; kk < 16; ++kk) {
            float a[4], b0[4], b1[4], b2[4];
            #pragma unroll
            for (int i = 0; i < 4; i++) a[i] = Xs[ty + i * 16][kk];
            #pragma unroll
            for (int j = 0; j < 4; j++) { b0[j] = B0[kk][tx + j * 16]; b1[j] = B1[kk][tx + j * 16]; b2[j] = B2[kk][tx + j * 16]; }
            #pragma unroll
            for (int i = 0; i < 4; i++)
                #pragma unroll
                for (int j = 0; j < 4; j++) {
                    aR[i][j] = fmaf(a[i], b0[j], aR[i][j]);
                    aI[i][j] = fmaf(a[i], b1[j], aI[i][j]);
                    aN[i][j] = fmaf(a[i], b2[j], aN[i][j]);
                }
        }
        __syncthreads();
    }
    // Phase 2: gh = hidden @ W_h   (K = 256)
    for (int k0 = 0; k0 < 256; k0 += 16) {
        {
            int m = tid >> 2, kc = (tid & 3) * 4;
            float4 v = *(const float4*)(hidden + (size_t)(bm + m) * 256 + k0 + kc);
            Xs[m][kc] = v.x; Xs[m][kc + 1] = v.y; Xs[m][kc + 2] = v.z; Xs[m][kc + 3] = v.w;
        }
        {
            int k = tid >> 4, c = (tid & 15) * 4;
            const float* wr = Wh + (size_t)(k0 + k) * 768 + bd + c;
            *(float4*)&B0[k][c] = *(const float4*)(wr);
            *(float4*)&B1[k][c] = *(const float4*)(wr + 256);
            *(float4*)&B2[k][c] = *(const float4*)(wr + 512);
        }
        __syncthreads();
        #pragma unroll
        for (int kk = 0; kk < 16; ++kk) {
            float a[4], b0[4], b1[4], b2[4];
            #pragma unroll
            for (int i = 0; i < 4; i++) a[i] = Xs[ty + i * 16][kk];
            #pragma unroll
            for (int j = 0; j < 4; j++) { b0[j] = B0[kk][tx + j * 16]; b1[j] = B1[kk][tx + j * 16]; b2[j] = B2[kk][tx + j * 16]; }
            #pragma unroll
            for (int i = 0; i < 4; i++)
                #pragma unroll
                for (int j = 0; j < 4; j++) {
                    hR[i][j] = fmaf(a[i], b0[j], hR[i][j]);
                    hI[i][j] = fmaf(a[i], b1[j], hI[i][j]);
                    hN[i][j] = fmaf(a[i], b2[j], hN[i][j]);
                }
        }
        __syncthreads();
    }
    // Gates epilogue
    #pragma unroll
    for (int i = 0; i < 4; i++) {
        int m = bm + ty + i * 16;
        #pragma unroll
        for (int j = 0; j < 4; j++) {
            int d = bd + tx + j * 16;
            float ir = aR[i][j] + bi[d]       + hR[i][j] + bh[d];
            float ii = aI[i][j] + bi[256 + d] + hI[i][j] + bh[256 + d];
            float in_ = aN[i][j] + bi[512 + d];
            float hn_ = hN[i][j] + bh[512 + d];
            float rg = sigmoidf_(ir);
            float ig = sigmoidf_(ii);
            float ng = tanhf(in_ + rg * hn_);
            float hv = hidden[(size_t)m * 256 + d];
            newh[(size_t)m * 256 + d] = ng + ig * (hv - ng);
        }
    }
}

// ---------------------------------------------------------------------------
// K5: attention readout.  One block per batch, thread d owns column d.
// ---------------------------------------------------------------------------
__global__ __launch_bounds__(256) void attn_kernel(
    const float* __restrict__ newh,
    const int* __restrict__ alias, const int* __restrict__ mask,
    const float* __restrict__ W1, const float* __restrict__ b1,
    const float* __restrict__ W2, const float* __restrict__ b2,
    const float* __restrict__ W3,
    float* __restrict__ ht_out, float* __restrict__ a_out)
{
    const int b = blockIdx.x;
    const int d = threadIdx.x;   // 0..255
    __shared__ float sh[256];
    __shared__ float q1s[256];
    __shared__ float red4[4];
    __shared__ int last_s;
    if (d == 0) {
        int s = 0;
        for (int l = 0; l < 64; ++l) s += mask[b * 64 + l];
        last_s = s - 1;
    }
    __syncthreads();
    const int last = last_s;
    const float* nb = newh + (size_t)b * 64 * 256;
    {
        int node = alias[b * 64 + last];
        float v = nb[(size_t)node * 256 + d];
        ht_out[b * 256 + d] = v;
        sh[d] = v;
    }
    __syncthreads();
    {
        float q0 = 0, q1v = 0, q2v = 0, q3v = 0;
        for (int k = 0; k < 256; k += 4) {
            q0  = fmaf(sh[k],     W1[(size_t)k * 256 + d],       q0);
            q1v = fmaf(sh[k + 1], W1[(size_t)(k + 1) * 256 + d], q1v);
            q2v = fmaf(sh[k + 2], W1[(size_t)(k + 2) * 256 + d], q2v);
            q3v = fmaf(sh[k + 3], W1[(size_t)(k + 3) * 256 + d], q3v);
        }
        q1s[d] = (q0 + q1v) + (q2v + q3v) + b1[d];
    }
    const float w3d = W3[d];
    float accA = 0.f;
    for (int l = 0; l < 64; ++l) {
        __syncthreads();
        int node = alias[b * 64 + l];
        float sv = nb[(size_t)node * 256 + d];
        sh[d] = sv;
        __syncthreads();
        float q0 = 0, q1v = 0, q2v = 0, q3v = 0;
        for (int k = 0; k < 256; k += 4) {
            q0  = fmaf(sh[k],     W2[(size_t)k * 256 + d],       q0);
            q1v = fmaf(sh[k + 1], W2[(size_t)(k + 1) * 256 + d], q1v);
            q2v = fmaf(sh[k + 2], W2[(size_t)(k + 2) * 256 + d], q2v);
            q3v = fmaf(sh[k + 3], W2[(size_t)(k + 3) * 256 + d], q3v);
        }
        float q2 = (q0 + q1v) + (q2v + q3v) + b2[d];
        float t = w3d * sigmoidf_(q1s[d] + q2);
        #pragma unroll
        for (int off = 32; off > 0; off >>= 1) t += __shfl_down(t, off);
        if ((d & 63) == 0) red4[d >> 6] = t;
        __syncthreads();
        float alpha = red4[0] + red4[1] + red4[2] + red4[3];
        float mf = (float)mask[b * 64 + l];
        accA = fmaf(alpha * mf, sv, accA);
    }
    a_out[b * 256 + d] = accA;
}

// ---------------------------------------------------------------------------
// K6: out = relu([a,ht] @ Wn1 + bn1) @ Wn2 + bn2
// ---------------------------------------------------------------------------
__global__ __launch_bounds__(256) void final_mlp(
    const float* __restrict__ a, const float* __restrict__ ht,
    const float* __restrict__ Wn1, const float* __restrict__ bn1,
    const float* __restrict__ Wn2, const float* __restrict__ bn2,
    float* __restrict__ out)
{
    const int b = blockIdx.x;
    const int d = threadIdx.x;
    __shared__ float xs[512];
    __shared__ float ys[256];
    xs[d] = a[b * 256 + d];
    xs[256 + d] = ht[b * 256 + d];
    __syncthreads();
    float y0 = 0, y1 = 0, y2 = 0, y3 = 0;
    for (int k = 0; k < 512; k += 4) {
        y0 = fmaf(xs[k],     Wn1[(size_t)k * 256 + d],       y0);
        y1 = fmaf(xs[k + 1], Wn1[(size_t)(k + 1) * 256 + d], y1);
        y2 = fmaf(xs[k + 2], Wn1[(size_t)(k + 2) * 256 + d], y2);
        y3 = fmaf(xs[k + 3], Wn1[(size_t)(k + 3) * 256 + d], y3);
    }
    ys[d] = fmaxf((y0 + y1) + (y2 + y3) + bn1[d], 0.f);
    __syncthreads();
    float o0 = 0, o1 = 0, o2 = 0, o3 = 0;
    for (int k = 0; k < 256; k += 4) {
        o0 = fmaf(ys[k],     Wn2[(size_t)k * 256 + d],       o0);
        o1 = fmaf(ys[k + 1], Wn2[(size_t)(k + 1) * 256 + d], o1);
        o2 = fmaf(ys[k + 2], Wn2[(size_t)(k + 2) * 256 + d], o2);
        o3 = fmaf(ys[k + 3], Wn2[(size_t)(k + 3) * 256 + d], o3);
    }
    out[b * 256 + d] = (o0 + o1) + (o2 + o3) + bn2[d];
}

// ---------------------------------------------------------------------------
extern "C" void kernel_launch(void* const* d_in, const int* in_sizes, int n_in,
                              void* d_out, int out_size, void* d_ws, size_t ws_size,
                              hipStream_t stream)
{
    const int*   alias  = (const int*)  d_in[0];
    const float* A      = (const float*)d_in[1];
    const int*   items  = (const int*)  d_in[2];
    const int*   mask   = (const int*)  d_in[3];
    const float* emb    = (const float*)d_in[4];
    const float* W_ein  = (const float*)d_in[5];
    const float* b_ein  = (const float*)d_in[6];
    const float* W_eout = (const float*)d_in[7];
    const float* b_eout = (const float*)d_in[8];
    const float* b_iah  = (const float*)d_in[9];
    const float* b_oah  = (const float*)d_in[10];
    const float* W_i    = (const float*)d_in[11];
    const float* b_i    = (const float*)d_in[12];
    const float* W_h    = (const float*)d_in[13];
    const float* b_h    = (const float*)d_in[14];
    const float* W1     = (const float*)d_in[15];
    const float* b1     = (const float*)d_in[16];
    const float* W2     = (const float*)d_in[17];
    const float* b2     = (const float*)d_in[18];
    const float* W3     = (const float*)d_in[19];
    const float* Wn1    = (const float*)d_in[20];
    const float* bn1    = (const float*)d_in[21];
    const float* Wn2    = (const float*)d_in[22];
    const float* bn2    = (const float*)d_in[23];
    float* out = (float*)d_out;
    (void)in_sizes; (void)n_in; (void)out_size; (void)ws_size;

    float* ws     = (float*)d_ws;
    float* hidden = ws;                    // 8,388,608 floats
    float* hio    = ws + 8388608;          // 16,777,216 floats
    float* inp    = ws + 25165824;         // 16,777,216 floats  (total 167.8 MB)
    float* newh   = hio;                   // reuse: hio dead after adj_mm
    float* ht     = inp;                   // reuse: inp dead after gru_fused
    float* a      = inp + 131072;

    gather_emb <<<8192, 256, 0, stream>>>(items, emb, hidden);
    gemm_hio   <<<dim3(256, 4), 256, 0, stream>>>(hidden, W_ein, b_ein, W_eout, b_eout, hio);
    adj_mm     <<<dim3(512, 4), 256, 0, stream>>>(A, hio, b_iah, b_oah, inp);
    gru_fused  <<<dim3(512, 4), 256, 0, stream>>>(inp, hidden, W_i, b_i, W_h, b_h, newh);
    attn_kernel<<<512, 256, 0, stream>>>(newh, alias, mask, W1, b1, W2, b2, W3, ht, a);
    final_mlp  <<<512, 256, 0, stream>>>(a, ht, Wn1, bn1, Wn2, bn2, out);
}

// Round 2
// 509.462 us; speedup vs baseline: 2.0176x; 2.0176x over previous
//
#include <hip/hip_runtime.h>
#include <hip/hip_bf16.h>
#include <math.h>

typedef short bhalf8 __attribute__((ext_vector_type(8)));
typedef float floatx4 __attribute__((ext_vector_type(4)));

__device__ __forceinline__ float sigmoidf_(float x) { return 1.0f / (1.0f + __expf(-x)); }

__device__ __forceinline__ unsigned short f2bf(float f) {
    unsigned int u = __builtin_bit_cast(unsigned int, f);
    u += 0x7FFFu + ((u >> 16) & 1u);
    return (unsigned short)(u >> 16);
}
__device__ __forceinline__ float bf2f(unsigned short h) {
    unsigned int u = ((unsigned int)h) << 16;
    return __builtin_bit_cast(float, u);
}

__device__ __forceinline__ floatx4 mfma16(bhalf8 a, bhalf8 b, floatx4 c) {
    return __builtin_amdgcn_mfma_f32_16x16x32_bf16(a, b, c, 0, 0, 0);
}

// ---------------------------------------------------------------------------
// P0: pack weights f32 [K][N] -> bf16 fragment-linear tiles (32k x BN n).
// Layout: t = ((kt*NT + nt)*FT + f)*512 + lane*8 + j
//   k = kt*32 + (lane>>4)*8 + j ; n = nt*BN + f*16 + (lane&15)
// Two-source variant: n < split -> W0 (stride=split), else W1 (stride=N-split)
// ---------------------------------------------------------------------------
__global__ __launch_bounds__(256) void pack_w(
    const float* __restrict__ W0, const float* __restrict__ W1, int split,
    int K, int N, int BN, unsigned short* __restrict__ out)
{
    int t = blockIdx.x * 256 + threadIdx.x;
    int j = t & 7;
    int lane = (t >> 3) & 63;
    int FT = BN >> 4;
    int f = (t >> 9) % FT;
    int rest = t / (512 * FT);
    int NT = N / BN;
    int nt = rest % NT;
    int kt = rest / NT;
    int k = kt * 32 + (lane >> 4) * 8 + j;
    int n = nt * BN + f * 16 + (lane & 15);
    float v = (n < split) ? W0[(size_t)k * split + n]
                          : W1[(size_t)k * (N - split) + (n - split)];
    out[t] = f2bf(v);
}

// ---------------------------------------------------------------------------
// K1: hidden_bf[B*N, 256] = bf16(emb[items])
// ---------------------------------------------------------------------------
__global__ __launch_bounds__(256) void gather_emb(
    const int* __restrict__ items, const float* __restrict__ emb,
    unsigned short* __restrict__ hidden_bf)
{
    int i = blockIdx.x * 256 + threadIdx.x;   // over B*N*256/8 chunks
    int row = i >> 5;                          // 32 chunks of 8 per row
    int c = (i & 31) * 8;
    int it = items[row];
    const float* src = emb + (size_t)it * 256 + c;
    float4 v0 = *(const float4*)src;
    float4 v1 = *(const float4*)(src + 4);
    uint4 o;
    o.x = f2bf(v0.x) | ((unsigned)f2bf(v0.y) << 16);
    o.y = f2bf(v0.z) | ((unsigned)f2bf(v0.w) << 16);
    o.z = f2bf(v1.x) | ((unsigned)f2bf(v1.y) << 16);
    o.w = f2bf(v1.z) | ((unsigned)f2bf(v1.w) << 16);
    *(uint4*)(hidden_bf + (size_t)row * 256 + c) = o;
}

// ---------------------------------------------------------------------------
// K2: hio = hidden @ [W_ein|W_eout] + bias, MFMA, output PACKED for adj_mm's
// B-operand: PB(b,half,ktb,f,lane,j) = ((((b*2+half)*2+ktb)*16+f)*64+lane)*8+j
// Tiles: BM=128, BN=128, BK=32. grid (256, 4), 256 thr (4 waves 2x2).
// ---------------------------------------------------------------------------
__global__ __launch_bounds__(256) void gemm_hio_mfma(
    const unsigned short* __restrict__ hidden_bf,
    const unsigned short* __restrict__ Wio_pk,
    const float* __restrict__ bein, const float* __restrict__ beout,
    unsigned short* __restrict__ hio_pk)
{
    __shared__ unsigned short As[4096];   // [8 mf][64 lane][8 j]
    __shared__ unsigned short Bs[4096];   // [8 nf][64 lane][8 j]
    const int tid = threadIdx.x;
    const int wid = tid >> 6, lane = tid & 63;
    const int wr = wid >> 1, wc = wid & 1;
    const int bm = blockIdx.x * 128;
    const int nt = blockIdx.y;            // n-tile of 128 within 512

    floatx4 acc[4][4] = {};
    for (int kt = 0; kt < 8; ++kt) {
        #pragma unroll
        for (int it = 0; it < 2; ++it) {
            int s = tid + it * 256;       // 512 chunks: r = s>>2, jj = s&3
            int r = s >> 2, jj = s & 3;
            uint4 v = *(const uint4*)(hidden_bf + (size_t)(bm + r) * 256 + kt * 32 + jj * 8);
            *(uint4*)&As[((r >> 4) * 64 + jj * 16 + (r & 15)) * 8] = v;
            uint4 w = *(const uint4*)(Wio_pk + ((size_t)(kt * 4 + nt) * 8) * 512 + s * 8);
            *(uint4*)&Bs[s * 8] = w;
        }
        __syncthreads();
        bhalf8 a[4], b[4];
        #pragma unroll
        for (int i = 0; i < 4; i++) a[i] = *(const bhalf8*)&As[((wr * 4 + i) * 64 + lane) * 8];
        #pragma unroll
        for (int j = 0; j < 4; j++) b[j] = *(const bhalf8*)&Bs[((wc * 4 + j) * 64 + lane) * 8];
        #pragma unroll
        for (int i = 0; i < 4; i++)
            #pragma unroll
            for (int j = 0; j < 4; j++) acc[i][j] = mfma16(a[i], b[j], acc[i][j]);
        __syncthreads();
    }
    // Epilogue: add bias, pack into adj-B layout
    const int r0 = (lane >> 4) * 4;
    #pragma unroll
    for (int mf = 0; mf < 4; mf++) {
        int m0 = bm + wr * 64 + mf * 16 + r0;
        int b_ = m0 >> 6;
        int ml = m0 & 63;
        int ktb = ml >> 5;
        int k0 = ml & 31;
        int j0 = k0 & 7;
        #pragma unroll
        for (int nf = 0; nf < 4; nf++) {
            int ng = nt * 128 + wc * 64 + nf * 16 + (lane & 15);
            int half = ng >> 8;
            int nh = ng & 255;
            float bias = half ? beout[nh] : bein[nh];
            int lane_b = ((k0 >> 3) << 4) + (nh & 15);
            size_t pb = ((((size_t)(b_ * 2 + half) * 2 + ktb) * 16 + (nh >> 4)) * 64 + lane_b) * 8 + j0;
            ushort4 o;
            o.x = f2bf(acc[mf][nf][0] + bias);
            o.y = f2bf(acc[mf][nf][1] + bias);
            o.z = f2bf(acc[mf][nf][2] + bias);
            o.w = f2bf(acc[mf][nf][3] + bias);
            *(ushort4*)(hio_pk + pb) = o;
        }
    }
}

// ---------------------------------------------------------------------------
// K3: inp[b,:,half*256:+256] = A_half[b] @ hio_half[b] + bias.  MFMA.
// grid (512, 2), 256 thr. BM=64, BN=256 (wave owns 64 cols), K=64 (2 kt).
// Output row-major bf16 [32768][512] (gru A-operand format).
// ---------------------------------------------------------------------------
__global__ __launch_bounds__(256) void adj_mfma(
    const float* __restrict__ A,
    const unsigned short* __restrict__ hio_pk,
    const float* __restrict__ biah, const float* __restrict__ boah,
    unsigned short* __restrict__ inp_bf)
{
    __shared__ unsigned short As_[2048];   // [4 mf][64][8]
    __shared__ unsigned short Bs_[8192];   // [16 nf][64][8]
    const int b = blockIdx.x;
    const int half = blockIdx.y;
    const int tid = threadIdx.x;
    const int wid = tid >> 6, lane = tid & 63;

    floatx4 acc[4][4] = {};
    for (int kt = 0; kt < 2; ++kt) {
        {   // stage adjacency (convert f32->bf16): 256 chunks of 8
            int r = tid >> 2, jj = tid & 3;
            const float* src = A + (size_t)b * 8192 + r * 128 + half * 64 + kt * 32 + jj * 8;
            float4 v0 = *(const float4*)src;
            float4 v1 = *(const float4*)(src + 4);
            uint4 o;
            o.x = f2bf(v0.x) | ((unsigned)f2bf(v0.y) << 16);
            o.y = f2bf(v0.z) | ((unsigned)f2bf(v0.w) << 16);
            o.z = f2bf(v1.x) | ((unsigned)f2bf(v1.y) << 16);
            o.w = f2bf(v1.z) | ((unsigned)f2bf(v1.w) << 16);
            *(uint4*)&As_[((r >> 4) * 64 + jj * 16 + (r & 15)) * 8] = o;
        }
        {   // stage B: linear copy of 16KB packed tile
            const unsigned short* src = hio_pk + ((size_t)((b * 2 + half) * 2 + kt) * 16 * 64) * 8;
            #pragma unroll
            for (int it = 0; it < 4; ++it) {
                int s = tid + it * 256;
                *(uint4*)&Bs_[s * 8] = *(const uint4*)(src + s * 8);
            }
        }
        __syncthreads();
        bhalf8 a[4], bb[4];
        #pragma unroll
        for (int i = 0; i < 4; i++) a[i] = *(const bhalf8*)&As_[(i * 64 + lane) * 8];
        #pragma unroll
        for (int j = 0; j < 4; j++) bb[j] = *(const bhalf8*)&Bs_[((wid * 4 + j) * 64 + lane) * 8];
        #pragma unroll
        for (int i = 0; i < 4; i++)
            #pragma unroll
            for (int j = 0; j < 4; j++) acc[i][j] = mfma16(a[i], bb[j], acc[i][j]);
        __syncthreads();
    }
    const float* bias = half ? boah : biah;
    const int r0 = (lane >> 4) * 4;
    #pragma unroll
    for (int i = 0; i < 4; i++) {
        #pragma unroll
        for (int j = 0; j < 4; j++) {
            int nh = wid * 64 + j * 16 + (lane & 15);
            float bv = bias[nh];
            #pragma unroll
            for (int reg = 0; reg < 4; reg++) {
                int m = i * 16 + r0 + reg;
                inp_bf[(size_t)(b * 64 + m) * 512 + half * 256 + nh] = f2bf(acc[i][j][reg] + bv);
            }
        }
    }
}

// ---------------------------------------------------------------------------
// K4: GRU cell, MFMA.  Joint K-loop over [inp(512) | hidden(256)].
// 4 accum sets: RI_r, RI_i (full K), I_n (K<512), H_n (K>=512).
// BM=128, BD=64. grid (256,4), 256 thr; wave owns 32 rows x 64 cols.
// ---------------------------------------------------------------------------
__global__ __launch_bounds__(256) void gru_mfma(
    const unsigned short* __restrict__ inp_bf,
    const unsigned short* __restrict__ hidden_bf,
    const unsigned short* __restrict__ Wi_pk,
    const unsigned short* __restrict__ Wh_pk,
    const float* __restrict__ bi, const float* __restrict__ bh,
    float* __restrict__ newh)
{
    __shared__ unsigned short As[4096];    // [8 mf][64][8]
    __shared__ unsigned short Bs[6144];    // 3 gates x [4 nf][64][8]
    const int tid = threadIdx.x;
    const int wid = tid >> 6, lane = tid & 63;
    const int bm = blockIdx.x * 128;
    const int dt = blockIdx.y;             // d tile (64 wide)
    const int bd = dt * 64;

    floatx4 R[2][4] = {}, I[2][4] = {}, N0[2][4] = {}, N1[2][4] = {};

    for (int kt = 0; kt < 24; ++kt) {
        const bool ph = kt < 16;
        // stage A (row-major activations): 512 chunks of 8
        #pragma unroll
        for (int it = 0; it < 2; ++it) {
            int s = tid + it * 256;
            int r = s >> 2, jj = s & 3;
            const unsigned short* src = ph
                ? inp_bf    + (size_t)(bm + r) * 512 + kt * 32 + jj * 8
                : hidden_bf + (size_t)(bm + r) * 256 + (kt - 16) * 32 + jj * 8;
            *(uint4*)&As[((r >> 4) * 64 + jj * 16 + (r & 15)) * 8] = *(const uint4*)src;
        }
        // stage B: 3 gate tiles of 4KB, linear copies
        const unsigned short* wbase = ph ? Wi_pk : Wh_pk;
        const int ktl = ph ? kt : kt - 16;
        #pragma unroll
        for (int g = 0; g < 3; ++g) {
            const unsigned short* src = wbase + ((size_t)(ktl * 12 + (g * 4 + dt)) * 4 * 64) * 8;
            *(uint4*)&Bs[(g * 256 + tid) * 8] = *(const uint4*)(src + tid * 8);
        }
        __syncthreads();
        bhalf8 a0 = *(const bhalf8*)&As[((wid * 2 + 0) * 64 + lane) * 8];
        bhalf8 a1 = *(const bhalf8*)&As[((wid * 2 + 1) * 64 + lane) * 8];
        {   // gate r
            #pragma unroll
            for (int j = 0; j < 4; j++) {
                bhalf8 bv = *(const bhalf8*)&Bs[(0 * 256 + (j * 64 + lane)) * 8];
                R[0][j] = mfma16(a0, bv, R[0][j]);
                R[1][j] = mfma16(a1, bv, R[1][j]);
            }
        }
        {   // gate i
            #pragma unroll
            for (int j = 0; j < 4; j++) {
                bhalf8 bv = *(const bhalf8*)&Bs[(1 * 256 + (j * 64 + lane)) * 8];
                I[0][j] = mfma16(a0, bv, I[0][j]);
                I[1][j] = mfma16(a1, bv, I[1][j]);
            }
        }
        if (ph) {  // gate n (input part)
            #pragma unroll
            for (int j = 0; j < 4; j++) {
                bhalf8 bv = *(const bhalf8*)&Bs[(2 * 256 + (j * 64 + lane)) * 8];
                N0[0][j] = mfma16(a0, bv, N0[0][j]);
                N0[1][j] = mfma16(a1, bv, N0[1][j]);
            }
        } else {   // gate n (hidden part)
            #pragma unroll
            for (int j = 0; j < 4; j++) {
                bhalf8 bv = *(const bhalf8*)&Bs[(2 * 256 + (j * 64 + lane)) * 8];
                N1[0][j] = mfma16(a0, bv, N1[0][j]);
                N1[1][j] = mfma16(a1, bv, N1[1][j]);
            }
        }
        __syncthreads();
    }
    // Gates epilogue
    const int r0 = (lane >> 4) * 4;
    #pragma unroll
    for (int i = 0; i < 2; i++) {
        #pragma unroll
        for (int j = 0; j < 4; j++) {
            int d = bd + j * 16 + (lane & 15);
            float bir = bi[d] + bh[d];
            float bii = bi[256 + d] + bh[256 + d];
            float bin = bi[512 + d];
            float bhn = bh[512 + d];
            #pragma unroll
            for (int reg = 0; reg < 4; reg++) {
                int m = bm + wid * 32 + i * 16 + r0 + reg;
                float rg = sigmoidf_(R[i][j][reg] + bir);
                float ig = sigmoidf_(I[i][j][reg] + bii);
                float ng = tanhf(N0[i][j][reg] + bin + rg * (N1[i][j][reg] + bhn));
                float hv = bf2f(hidden_bf[(size_t)m * 256 + d]);
                newh[(size_t)m * 256 + d] = ng + ig * (hv - ng);
            }
        }
    }
}

// ---------------------------------------------------------------------------
// K5: attention readout (f32).  One block per batch, thread d owns column d.
// ---------------------------------------------------------------------------
__global__ __launch_bounds__(256) void attn_kernel(
    const float* __restrict__ newh,
    const int* __restrict__ alias, const int* __restrict__ mask,
    const float* __restrict__ W1, const float* __restrict__ b1,
    const float* __restrict__ W2, const float* __restrict__ b2,
    const float* __restrict__ W3,
    float* __restrict__ ht_out, float* __restrict__ a_out)
{
    const int b = blockIdx.x;
    const int d = threadIdx.x;   // 0..255
    __shared__ float sh[256];
    __shared__ float q1s[256];
    __shared__ float red4[4];
    __shared__ int last_s;
    if (d == 0) {
        int s = 0;
        for (int l = 0; l < 64; ++l) s += mask[b * 64 + l];
        last_s = s - 1;
    }
    __syncthreads();
    const int last = last_s;
    const float* nb = newh + (size_t)b * 64 * 256;
    {
        int node = alias[b * 64 + last];
        float v = nb[(size_t)node * 256 + d];
        ht_out[b * 256 + d] = v;
        sh[d] = v;
    }
    __syncthreads();
    {
        float q0 = 0, q1v = 0, q2v = 0, q3v = 0;
        for (int k = 0; k < 256; k += 4) {
            q0  = fmaf(sh[k],     W1[(size_t)k * 256 + d],       q0);
            q1v = fmaf(sh[k + 1], W1[(size_t)(k + 1) * 256 + d], q1v);
            q2v = fmaf(sh[k + 2], W1[(size_t)(k + 2) * 256 + d], q2v);
            q3v = fmaf(sh[k + 3], W1[(size_t)(k + 3) * 256 + d], q3v);
        }
        q1s[d] = (q0 + q1v) + (q2v + q3v) + b1[d];
    }
    const float w3d = W3[d];
    float accA = 0.f;
    for (int l = 0; l < 64; ++l) {
        __syncthreads();
        int node = alias[b * 64 + l];
        float sv = nb[(size_t)node * 256 + d];
        sh[d] = sv;
        __syncthreads();
        float q0 = 0, q1v = 0, q2v = 0, q3v = 0;
        for (int k = 0; k < 256; k += 4) {
            q0  = fmaf(sh[k],     W2[(size_t)k * 256 + d],       q0);
            q1v = fmaf(sh[k + 1], W2[(size_t)(k + 1) * 256 + d], q1v);
            q2v = fmaf(sh[k + 2], W2[(size_t)(k + 2) * 256 + d], q2v);
            q3v = fmaf(sh[k + 3], W2[(size_t)(k + 3) * 256 + d], q3v);
        }
        float q2 = (q0 + q1v) + (q2v + q3v) + b2[d];
        float t = w3d * sigmoidf_(q1s[d] + q2);
        #pragma unroll
        for (int off = 32; off > 0; off >>= 1) t += __shfl_down(t, off);
        if ((d & 63) == 0) red4[d >> 6] = t;
        __syncthreads();
        float alpha = red4[0] + red4[1] + red4[2] + red4[3];
        float mf = (float)mask[b * 64 + l];
        accA = fmaf(alpha * mf, sv, accA);
    }
    a_out[b * 256 + d] = accA;
}

// ---------------------------------------------------------------------------
// K6: out = relu([a,ht] @ Wn1 + bn1) @ Wn2 + bn2
// ---------------------------------------------------------------------------
__global__ __launch_bounds__(256) void final_mlp(
    const float* __restrict__ a, const float* __restrict__ ht,
    const float* __restrict__ Wn1, const float* __restrict__ bn1,
    const float* __restrict__ Wn2, const float* __restrict__ bn2,
    float* __restrict__ out)
{
    const int b = blockIdx.x;
    const int d = threadIdx.x;
    __shared__ float xs[512];
    __shared__ float ys[256];
    xs[d] = a[b * 256 + d];
    xs[256 + d] = ht[b * 256 + d];
    __syncthreads();
    float y0 = 0, y1 = 0, y2 = 0, y3 = 0;
    for (int k = 0; k < 512; k += 4) {
        y0 = fmaf(xs[k],     Wn1[(size_t)k * 256 + d],       y0);
        y1 = fmaf(xs[k + 1], Wn1[(size_t)(k + 1) * 256 + d], y1);
        y2 = fmaf(xs[k + 2], Wn1[(size_t)(k + 2) * 256 + d], y2);
        y3 = fmaf(xs[k + 3], Wn1[(size_t)(k + 3) * 256 + d], y3);
    }
    ys[d] = fmaxf((y0 + y1) + (y2 + y3) + bn1[d], 0.f);
    __syncthreads();
    float o0 = 0, o1 = 0, o2 = 0, o3 = 0;
    for (int k = 0; k < 256; k += 4) {
        o0 = fmaf(ys[k],     Wn2[(size_t)k * 256 + d],       o0);
        o1 = fmaf(ys[k + 1], Wn2[(size_t)(k + 1) * 256 + d], o1);
        o2 = fmaf(ys[k + 2], Wn2[(size_t)(k + 2) * 256 + d], o2);
        o3 = fmaf(ys[k + 3], Wn2[(size_t)(k + 3) * 256 + d], o3);
    }
    out[b * 256 + d] = (o0 + o1) + (o2 + o3) + bn2[d];
}

// ---------------------------------------------------------------------------
extern "C" void kernel_launch(void* const* d_in, const int* in_sizes, int n_in,
                              void* d_out, int out_size, void* d_ws, size_t ws_size,
                              hipStream_t stream)
{
    const int*   alias  = (const int*)  d_in[0];
    const float* A      = (const float*)d_in[1];
    const int*   items  = (const int*)  d_in[2];
    const int*   mask   = (const int*)  d_in[3];
    const float* emb    = (const float*)d_in[4];
    const float* W_ein  = (const float*)d_in[5];
    const float* b_ein  = (const float*)d_in[6];
    const float* W_eout = (const float*)d_in[7];
    const float* b_eout = (const float*)d_in[8];
    const float* b_iah  = (const float*)d_in[9];
    const float* b_oah  = (const float*)d_in[10];
    const float* W_i    = (const float*)d_in[11];
    const float* b_i    = (const float*)d_in[12];
    const float* W_h    = (const float*)d_in[13];
    const float* b_h    = (const float*)d_in[14];
    const float* W1     = (const float*)d_in[15];
    const float* b1     = (const float*)d_in[16];
    const float* W2     = (const float*)d_in[17];
    const float* b2     = (const float*)d_in[18];
    const float* W3     = (const float*)d_in[19];
    const float* Wn1    = (const float*)d_in[20];
    const float* bn1    = (const float*)d_in[21];
    const float* Wn2    = (const float*)d_in[22];
    const float* bn2    = (const float*)d_in[23];
    float* out = (float*)d_out;
    (void)in_sizes; (void)n_in; (void)out_size; (void)ws_size;

    char* w = (char*)d_ws;
    unsigned short* hidden_bf = (unsigned short*)(w);                 // 16,777,216 B
    unsigned short* hio_pk    = (unsigned short*)(w + 16777216);      // 33,554,432 B
    unsigned short* inp_bf    = (unsigned short*)(w + 50331648);      // 33,554,432 B
    float*          newh      = (float*)         (w + 83886080);      // 33,554,432 B
    unsigned short* Wio_pk    = (unsigned short*)(w + 117440512);     //    262,144 B
    unsigned short* Wi_pk     = (unsigned short*)(w + 117702656);     //    786,432 B
    unsigned short* Wh_pk     = (unsigned short*)(w + 118489088);     //    393,216 B
    float*          ht        = (float*)         (w + 118882304);     //    524,288 B
    float*          a_buf     = (float*)         (w + 119406592);     //    524,288 B

    // pack weights (bf16, MFMA fragment order)
    pack_w<<<512,  256, 0, stream>>>(W_ein, W_eout, 256, 256, 512, 128, Wio_pk);
    pack_w<<<1536, 256, 0, stream>>>(W_i,   W_i,    768, 512, 768,  64, Wi_pk);
    pack_w<<<768,  256, 0, stream>>>(W_h,   W_h,    768, 256, 768,  64, Wh_pk);

    gather_emb   <<<4096, 256, 0, stream>>>(items, emb, hidden_bf);
    gemm_hio_mfma<<<dim3(256, 4), 256, 0, stream>>>(hidden_bf, Wio_pk, b_ein, b_eout, hio_pk);
    adj_mfma     <<<dim3(512, 2), 256, 0, stream>>>(A, hio_pk, b_iah, b_oah, inp_bf);
    gru_mfma     <<<dim3(256, 4), 256, 0, stream>>>(inp_bf, hidden_bf, Wi_pk, Wh_pk, b_i, b_h, newh);
    attn_kernel  <<<512, 256, 0, stream>>>(newh, alias, mask, W1, b1, W2, b2, W3, ht, a_buf);
    final_mlp    <<<512, 256, 0, stream>>>(a_buf, ht, Wn1, bn1, Wn2, bn2, out);
}

// Round 3
// 256.356 us; speedup vs baseline: 4.0097x; 1.9873x over previous
//
#include <hip/hip_runtime.h>
#include <hip/hip_bf16.h>
#include <math.h>

typedef short bhalf8 __attribute__((ext_vector_type(8)));
typedef float floatx4 __attribute__((ext_vector_type(4)));

__device__ __forceinline__ float sigmoidf_(float x) { return 1.0f / (1.0f + __expf(-x)); }

__device__ __forceinline__ unsigned short f2bf(float f) {
    unsigned int u = __builtin_bit_cast(unsigned int, f);
    u += 0x7FFFu + ((u >> 16) & 1u);
    return (unsigned short)(u >> 16);
}
__device__ __forceinline__ float bf2f(unsigned short h) {
    unsigned int u = ((unsigned int)h) << 16;
    return __builtin_bit_cast(float, u);
}

__device__ __forceinline__ floatx4 mfma16(bhalf8 a, bhalf8 b, floatx4 c) {
    return __builtin_amdgcn_mfma_f32_16x16x32_bf16(a, b, c, 0, 0, 0);
}

// ---------------------------------------------------------------------------
// P0: pack weights f32 [K][N] -> bf16 fragment-linear tiles.
// t = ((kt*NT + nt)*FT + f)*512 + lane*8 + j
//   k = kt*32 + (lane>>4)*8 + j ; n = nt*BN + f*16 + (lane&15)
// n < split -> W0 (row stride split), else W1 (row stride N-split)
// ---------------------------------------------------------------------------
__global__ __launch_bounds__(256) void pack_w(
    const float* __restrict__ W0, const float* __restrict__ W1, int split,
    int K, int N, int BN, unsigned short* __restrict__ out)
{
    int t = blockIdx.x * 256 + threadIdx.x;
    int j = t & 7;
    int lane = (t >> 3) & 63;
    int FT = BN >> 4;
    int f = (t >> 9) % FT;
    int rest = t / (512 * FT);
    int NT = N / BN;
    int nt = rest % NT;
    int kt = rest / NT;
    int k = kt * 32 + (lane >> 4) * 8 + j;
    int n = nt * BN + f * 16 + (lane & 15);
    float v = (n < split) ? W0[(size_t)k * split + n]
                          : W1[(size_t)k * (N - split) + (n - split)];
    out[t] = f2bf(v);
}

// ---------------------------------------------------------------------------
// K1: hidden_bf[B*N, 256] = bf16(emb[items])
// ---------------------------------------------------------------------------
__global__ __launch_bounds__(256) void gather_emb(
    const int* __restrict__ items, const float* __restrict__ emb,
    unsigned short* __restrict__ hidden_bf)
{
    int i = blockIdx.x * 256 + threadIdx.x;
    int row = i >> 5;
    int c = (i & 31) * 8;
    int it = items[row];
    const float* src = emb + (size_t)it * 256 + c;
    float4 v0 = *(const float4*)src;
    float4 v1 = *(const float4*)(src + 4);
    uint4 o;
    o.x = f2bf(v0.x) | ((unsigned)f2bf(v0.y) << 16);
    o.y = f2bf(v0.z) | ((unsigned)f2bf(v0.w) << 16);
    o.z = f2bf(v1.x) | ((unsigned)f2bf(v1.y) << 16);
    o.w = f2bf(v1.z) | ((unsigned)f2bf(v1.w) << 16);
    *(uint4*)(hidden_bf + (size_t)row * 256 + c) = o;
}

// ---------------------------------------------------------------------------
// K2: hio = hidden @ [W_ein|W_eout] + bias -> packed for adj B-operand.
// ---------------------------------------------------------------------------
__global__ __launch_bounds__(256) void gemm_hio_mfma(
    const unsigned short* __restrict__ hidden_bf,
    const unsigned short* __restrict__ Wio_pk,
    const float* __restrict__ bein, const float* __restrict__ beout,
    unsigned short* __restrict__ hio_pk)
{
    __shared__ unsigned short As[4096];
    __shared__ unsigned short Bs[4096];
    const int tid = threadIdx.x;
    const int wid = tid >> 6, lane = tid & 63;
    const int wr = wid >> 1, wc = wid & 1;
    const int bm = blockIdx.x * 128;
    const int nt = blockIdx.y;

    floatx4 acc[4][4] = {};
    for (int kt = 0; kt < 8; ++kt) {
        #pragma unroll
        for (int it = 0; it < 2; ++it) {
            int s = tid + it * 256;
            int r = s >> 2, jj = s & 3;
            uint4 v = *(const uint4*)(hidden_bf + (size_t)(bm + r) * 256 + kt * 32 + jj * 8);
            *(uint4*)&As[((r >> 4) * 64 + jj * 16 + (r & 15)) * 8] = v;
            uint4 w = *(const uint4*)(Wio_pk + ((size_t)(kt * 4 + nt) * 8) * 512 + s * 8);
            *(uint4*)&Bs[s * 8] = w;
        }
        __syncthreads();
        bhalf8 a[4], b[4];
        #pragma unroll
        for (int i = 0; i < 4; i++) a[i] = *(const bhalf8*)&As[((wr * 4 + i) * 64 + lane) * 8];
        #pragma unroll
        for (int j = 0; j < 4; j++) b[j] = *(const bhalf8*)&Bs[((wc * 4 + j) * 64 + lane) * 8];
        #pragma unroll
        for (int i = 0; i < 4; i++)
            #pragma unroll
            for (int j = 0; j < 4; j++) acc[i][j] = mfma16(a[i], b[j], acc[i][j]);
        __syncthreads();
    }
    const int r0 = (lane >> 4) * 4;
    #pragma unroll
    for (int mf = 0; mf < 4; mf++) {
        int m0 = bm + wr * 64 + mf * 16 + r0;
        int b_ = m0 >> 6;
        int ml = m0 & 63;
        int ktb = ml >> 5;
        int k0 = ml & 31;
        int j0 = k0 & 7;
        #pragma unroll
        for (int nf = 0; nf < 4; nf++) {
            int ng = nt * 128 + wc * 64 + nf * 16 + (lane & 15);
            int half = ng >> 8;
            int nh = ng & 255;
            float bias = half ? beout[nh] : bein[nh];
            int lane_b = ((k0 >> 3) << 4) + (nh & 15);
            size_t pb = ((((size_t)(b_ * 2 + half) * 2 + ktb) * 16 + (nh >> 4)) * 64 + lane_b) * 8 + j0;
            ushort4 o;
            o.x = f2bf(acc[mf][nf][0] + bias);
            o.y = f2bf(acc[mf][nf][1] + bias);
            o.z = f2bf(acc[mf][nf][2] + bias);
            o.w = f2bf(acc[mf][nf][3] + bias);
            *(ushort4*)(hio_pk + pb) = o;
        }
    }
}

// ---------------------------------------------------------------------------
// K3: inp = A_half @ hio_half + bias -> row-major bf16 [32768][512]
// ---------------------------------------------------------------------------
__global__ __launch_bounds__(256) void adj_mfma(
    const float* __restrict__ A,
    const unsigned short* __restrict__ hio_pk,
    const float* __restrict__ biah, const float* __restrict__ boah,
    unsigned short* __restrict__ inp_bf)
{
    __shared__ unsigned short As_[2048];
    __shared__ unsigned short Bs_[8192];
    const int b = blockIdx.x;
    const int half = blockIdx.y;
    const int tid = threadIdx.x;
    const int wid = tid >> 6, lane = tid & 63;

    floatx4 acc[4][4] = {};
    for (int kt = 0; kt < 2; ++kt) {
        {
            int r = tid >> 2, jj = tid & 3;
            const float* src = A + (size_t)b * 8192 + r * 128 + half * 64 + kt * 32 + jj * 8;
            float4 v0 = *(const float4*)src;
            float4 v1 = *(const float4*)(src + 4);
            uint4 o;
            o.x = f2bf(v0.x) | ((unsigned)f2bf(v0.y) << 16);
            o.y = f2bf(v0.z) | ((unsigned)f2bf(v0.w) << 16);
            o.z = f2bf(v1.x) | ((unsigned)f2bf(v1.y) << 16);
            o.w = f2bf(v1.z) | ((unsigned)f2bf(v1.w) << 16);
            *(uint4*)&As_[((r >> 4) * 64 + jj * 16 + (r & 15)) * 8] = o;
        }
        {
            const unsigned short* src = hio_pk + ((size_t)((b * 2 + half) * 2 + kt) * 16 * 64) * 8;
            #pragma unroll
            for (int it = 0; it < 4; ++it) {
                int s = tid + it * 256;
                *(uint4*)&Bs_[s * 8] = *(const uint4*)(src + s * 8);
            }
        }
        __syncthreads();
        bhalf8 a[4], bb[4];
        #pragma unroll
        for (int i = 0; i < 4; i++) a[i] = *(const bhalf8*)&As_[(i * 64 + lane) * 8];
        #pragma unroll
        for (int j = 0; j < 4; j++) bb[j] = *(const bhalf8*)&Bs_[((wid * 4 + j) * 64 + lane) * 8];
        #pragma unroll
        for (int i = 0; i < 4; i++)
            #pragma unroll
            for (int j = 0; j < 4; j++) acc[i][j] = mfma16(a[i], bb[j], acc[i][j]);
        __syncthreads();
    }
    const float* bias = half ? boah : biah;
    const int r0 = (lane >> 4) * 4;
    #pragma unroll
    for (int i = 0; i < 4; i++) {
        #pragma unroll
        for (int j = 0; j < 4; j++) {
            int nh = wid * 64 + j * 16 + (lane & 15);
            float bv = bias[nh];
            #pragma unroll
            for (int reg = 0; reg < 4; reg++) {
                int m = i * 16 + r0 + reg;
                inp_bf[(size_t)(b * 64 + m) * 512 + half * 256 + nh] = f2bf(acc[i][j][reg] + bv);
            }
        }
    }
}

// ---------------------------------------------------------------------------
// K4: GRU cell, MFMA; writes newh as bf16.
// ---------------------------------------------------------------------------
__global__ __launch_bounds__(256) void gru_mfma(
    const unsigned short* __restrict__ inp_bf,
    const unsigned short* __restrict__ hidden_bf,
    const unsigned short* __restrict__ Wi_pk,
    const unsigned short* __restrict__ Wh_pk,
    const float* __restrict__ bi, const float* __restrict__ bh,
    unsigned short* __restrict__ newh_bf)
{
    __shared__ unsigned short As[4096];
    __shared__ unsigned short Bs[6144];
    const int tid = threadIdx.x;
    const int wid = tid >> 6, lane = tid & 63;
    const int bm = blockIdx.x * 128;
    const int dt = blockIdx.y;
    const int bd = dt * 64;

    floatx4 R[2][4] = {}, I[2][4] = {}, N0[2][4] = {}, N1[2][4] = {};

    for (int kt = 0; kt < 24; ++kt) {
        const bool ph = kt < 16;
        #pragma unroll
        for (int it = 0; it < 2; ++it) {
            int s = tid + it * 256;
            int r = s >> 2, jj = s & 3;
            const unsigned short* src = ph
                ? inp_bf    + (size_t)(bm + r) * 512 + kt * 32 + jj * 8
                : hidden_bf + (size_t)(bm + r) * 256 + (kt - 16) * 32 + jj * 8;
            *(uint4*)&As[((r >> 4) * 64 + jj * 16 + (r & 15)) * 8] = *(const uint4*)src;
        }
        const unsigned short* wbase = ph ? Wi_pk : Wh_pk;
        const int ktl = ph ? kt : kt - 16;
        #pragma unroll
        for (int g = 0; g < 3; ++g) {
            const unsigned short* src = wbase + ((size_t)(ktl * 12 + (g * 4 + dt)) * 4 * 64) * 8;
            *(uint4*)&Bs[(g * 256 + tid) * 8] = *(const uint4*)(src + tid * 8);
        }
        __syncthreads();
        bhalf8 a0 = *(const bhalf8*)&As[((wid * 2 + 0) * 64 + lane) * 8];
        bhalf8 a1 = *(const bhalf8*)&As[((wid * 2 + 1) * 64 + lane) * 8];
        {
            #pragma unroll
            for (int j = 0; j < 4; j++) {
                bhalf8 bv = *(const bhalf8*)&Bs[(0 * 256 + (j * 64 + lane)) * 8];
                R[0][j] = mfma16(a0, bv, R[0][j]);
                R[1][j] = mfma16(a1, bv, R[1][j]);
            }
        }
        {
            #pragma unroll
            for (int j = 0; j < 4; j++) {
                bhalf8 bv = *(const bhalf8*)&Bs[(1 * 256 + (j * 64 + lane)) * 8];
                I[0][j] = mfma16(a0, bv, I[0][j]);
                I[1][j] = mfma16(a1, bv, I[1][j]);
            }
        }
        if (ph) {
            #pragma unroll
            for (int j = 0; j < 4; j++) {
                bhalf8 bv = *(const bhalf8*)&Bs[(2 * 256 + (j * 64 + lane)) * 8];
                N0[0][j] = mfma16(a0, bv, N0[0][j]);
                N0[1][j] = mfma16(a1, bv, N0[1][j]);
            }
        } else {
            #pragma unroll
            for (int j = 0; j < 4; j++) {
                bhalf8 bv = *(const bhalf8*)&Bs[(2 * 256 + (j * 64 + lane)) * 8];
                N1[0][j] = mfma16(a0, bv, N1[0][j]);
                N1[1][j] = mfma16(a1, bv, N1[1][j]);
            }
        }
        __syncthreads();
    }
    const int r0 = (lane >> 4) * 4;
    #pragma unroll
    for (int i = 0; i < 2; i++) {
        #pragma unroll
        for (int j = 0; j < 4; j++) {
            int d = bd + j * 16 + (lane & 15);
            float bir = bi[d] + bh[d];
            float bii = bi[256 + d] + bh[256 + d];
            float bin = bi[512 + d];
            float bhn = bh[512 + d];
            #pragma unroll
            for (int reg = 0; reg < 4; reg++) {
                int m = bm + wid * 32 + i * 16 + r0 + reg;
                float rg = sigmoidf_(R[i][j][reg] + bir);
                float ig = sigmoidf_(I[i][j][reg] + bii);
                float ng = tanhf(N0[i][j][reg] + bin + rg * (N1[i][j][reg] + bhn));
                float hv = bf2f(hidden_bf[(size_t)m * 256 + d]);
                newh_bf[(size_t)m * 256 + d] = f2bf(ng + ig * (hv - ng));
            }
        }
    }
}

// ---------------------------------------------------------------------------
// K5: per-batch last index + ht gather (bf16). One wave per batch.
// ---------------------------------------------------------------------------
__global__ __launch_bounds__(256) void prep_ht(
    const unsigned short* __restrict__ newh_bf,
    const int* __restrict__ alias, const int* __restrict__ mask,
    unsigned short* __restrict__ ht_bf)
{
    int b = blockIdx.x * 4 + (threadIdx.x >> 6);
    int lane = threadIdx.x & 63;
    int mv = mask[b * 64 + lane];
    #pragma unroll
    for (int off = 32; off > 0; off >>= 1) mv += __shfl_xor(mv, off);
    int last = mv - 1;
    int node = alias[b * 64 + last];
    const unsigned short* src = newh_bf + (size_t)(b * 64 + node) * 256;
    unsigned short* dst = ht_bf + (size_t)b * 256;
    if (lane < 32) *(uint4*)(dst + lane * 8) = *(const uint4*)(src + lane * 8);
}

// ---------------------------------------------------------------------------
// K6: generic small MFMA GEMM, BM=128, BN=128, N(out stride)=256.
// CONCAT: A row = [A0 row (256) | A1 row (256)], K=512.
// ---------------------------------------------------------------------------
template<int KT, bool CONCAT, bool RELU, bool OUTBF>
__global__ __launch_bounds__(256) void gemm_small(
    const unsigned short* __restrict__ A0, const unsigned short* __restrict__ A1,
    const unsigned short* __restrict__ Bpk, const float* __restrict__ bias,
    void* __restrict__ outp, int NT)
{
    __shared__ unsigned short As[4096];
    __shared__ unsigned short Bs[4096];
    const int tid = threadIdx.x;
    const int wid = tid >> 6, lane = tid & 63;
    const int wr = wid >> 1, wc = wid & 1;
    const int bm = blockIdx.x * 128, nt = blockIdx.y;

    floatx4 acc[4][4] = {};
    for (int kt = 0; kt < KT; ++kt) {
        #pragma unroll
        for (int it = 0; it < 2; ++it) {
            int s = tid + it * 256;
            int r = s >> 2, jj = s & 3;
            const unsigned short* src;
            if (CONCAT) {
                src = ((kt < 8) ? A0 : A1) + (size_t)(bm + r) * 256 + (kt & 7) * 32 + jj * 8;
            } else {
                src = A0 + (size_t)(bm + r) * 256 + kt * 32 + jj * 8;
            }
            *(uint4*)&As[((r >> 4) * 64 + jj * 16 + (r & 15)) * 8] = *(const uint4*)src;
            const unsigned short* bsrc = Bpk + ((size_t)(kt * NT + nt) * 8) * 512;
            *(uint4*)&Bs[s * 8] = *(const uint4*)(bsrc + s * 8);
        }
        __syncthreads();
        bhalf8 a[4], bb[4];
        #pragma unroll
        for (int i = 0; i < 4; i++) a[i] = *(const bhalf8*)&As[((wr * 4 + i) * 64 + lane) * 8];
        #pragma unroll
        for (int j = 0; j < 4; j++) bb[j] = *(const bhalf8*)&Bs[((wc * 4 + j) * 64 + lane) * 8];
        #pragma unroll
        for (int i = 0; i < 4; i++)
            #pragma unroll
            for (int j = 0; j < 4; j++) acc[i][j] = mfma16(a[i], bb[j], acc[i][j]);
        __syncthreads();
    }
    const int r0 = (lane >> 4) * 4;
    #pragma unroll
    for (int i = 0; i < 4; i++) {
        #pragma unroll
        for (int j = 0; j < 4; j++) {
            int col = nt * 128 + wc * 64 + j * 16 + (lane & 15);
            float bv = bias[col];
            #pragma unroll
            for (int reg = 0; reg < 4; reg++) {
                int m = bm + wr * 64 + i * 16 + r0 + reg;
                float v = acc[i][j][reg] + bv;
                if (RELU) v = fmaxf(v, 0.f);
                if (OUTBF) ((unsigned short*)outp)[(size_t)m * 256 + col] = f2bf(v);
                else       ((float*)outp)[(size_t)m * 256 + col] = v;
            }
        }
    }
}

// ---------------------------------------------------------------------------
// K7: fused attention. One block per batch: q2 GEMM (64x256, K=256 over
// alias-gathered newh rows), alpha = sigmoid(q1+q2)@W3 via shfl row-reduce,
// a = sum_l alpha*mask*seq -> bf16.
// ---------------------------------------------------------------------------
__global__ __launch_bounds__(256) void attn_fused(
    const unsigned short* __restrict__ newh_bf,
    const int* __restrict__ alias, const int* __restrict__ mask,
    const float* __restrict__ q1, const float* __restrict__ b2,
    const float* __restrict__ W3,
    const unsigned short* __restrict__ W2pk,
    unsigned short* __restrict__ a_bf)
{
    const int b = blockIdx.x;
    const int tid = threadIdx.x;
    const int wid = tid >> 6, lane = tid & 63;
    __shared__ int arow[64];
    __shared__ float alphap[4][64];
    __shared__ float am[64];
    __shared__ unsigned short As[2048];   // 64 x 32
    __shared__ unsigned short Bs[8192];   // 256 x 32
    if (tid < 64) arow[tid] = b * 64 + alias[b * 64 + tid];
    __syncthreads();

    floatx4 acc[4][4] = {};
    for (int kt = 0; kt < 8; ++kt) {
        {
            int r = tid >> 2, jj = tid & 3;
            const unsigned short* src = newh_bf + (size_t)arow[r] * 256 + kt * 32 + jj * 8;
            *(uint4*)&As[((r >> 4) * 64 + jj * 16 + (r & 15)) * 8] = *(const uint4*)src;
        }
        {
            const unsigned short* src = W2pk + (size_t)kt * 16 * 512;
            #pragma unroll
            for (int it = 0; it < 4; ++it) {
                int s = tid + it * 256;
                *(uint4*)&Bs[s * 8] = *(const uint4*)(src + s * 8);
            }
        }
        __syncthreads();
        bhalf8 a[4], bb[4];
        #pragma unroll
        for (int i = 0; i < 4; i++) a[i] = *(const bhalf8*)&As[(i * 64 + lane) * 8];
        #pragma unroll
        for (int j = 0; j < 4; j++) bb[j] = *(const bhalf8*)&Bs[((wid * 4 + j) * 64 + lane) * 8];
        #pragma unroll
        for (int i = 0; i < 4; i++)
            #pragma unroll
            for (int j = 0; j < 4; j++) acc[i][j] = mfma16(a[i], bb[j], acc[i][j]);
        __syncthreads();
    }
    // alpha: t = sigmoid(q1 + q2 + b2) * W3, reduce over 256 cols
    float q1v[4], b2v[4], w3v[4];
    #pragma unroll
    for (int j = 0; j < 4; j++) {
        int col = wid * 64 + j * 16 + (lane & 15);
        q1v[j] = q1[(size_t)b * 256 + col];
        b2v[j] = b2[col];
        w3v[j] = W3[col];
    }
    #pragma unroll
    for (int i = 0; i < 4; i++) {
        #pragma unroll
        for (int reg = 0; reg < 4; reg++) {
            float t = 0.f;
            #pragma unroll
            for (int j = 0; j < 4; j++)
                t += sigmoidf_(acc[i][j][reg] + q1v[j] + b2v[j]) * w3v[j];
            #pragma unroll
            for (int off = 1; off < 16; off <<= 1) t += __shfl_xor(t, off);
            if ((lane & 15) == 0) alphap[wid][i * 16 + (lane >> 4) * 4 + reg] = t;
        }
    }
    __syncthreads();
    if (tid < 64) {
        float al = alphap[0][tid] + alphap[1][tid] + alphap[2][tid] + alphap[3][tid];
        am[tid] = al * (float)mask[b * 64 + tid];
    }
    __syncthreads();
    float acca = 0.f;
    for (int l = 0; l < 64; ++l)
        acca = fmaf(am[l], bf2f(newh_bf[(size_t)arow[l] * 256 + tid]), acca);
    a_bf[(size_t)b * 256 + tid] = f2bf(acca);
}

// ---------------------------------------------------------------------------
extern "C" void kernel_launch(void* const* d_in, const int* in_sizes, int n_in,
                              void* d_out, int out_size, void* d_ws, size_t ws_size,
                              hipStream_t stream)
{
    const int*   alias  = (const int*)  d_in[0];
    const float* A      = (const float*)d_in[1];
    const int*   items  = (const int*)  d_in[2];
    const int*   mask   = (const int*)  d_in[3];
    const float* emb    = (const float*)d_in[4];
    const float* W_ein  = (const float*)d_in[5];
    const float* b_ein  = (const float*)d_in[6];
    const float* W_eout = (const float*)d_in[7];
    const float* b_eout = (const float*)d_in[8];
    const float* b_iah  = (const float*)d_in[9];
    const float* b_oah  = (const float*)d_in[10];
    const float* W_i    = (const float*)d_in[11];
    const float* b_i    = (const float*)d_in[12];
    const float* W_h    = (const float*)d_in[13];
    const float* b_h    = (const float*)d_in[14];
    const float* W1     = (const float*)d_in[15];
    const float* b1     = (const float*)d_in[16];
    const float* W2     = (const float*)d_in[17];
    const float* b2     = (const float*)d_in[18];
    const float* W3     = (const float*)d_in[19];
    const float* Wn1    = (const float*)d_in[20];
    const float* bn1    = (const float*)d_in[21];
    const float* Wn2    = (const float*)d_in[22];
    const float* bn2    = (const float*)d_in[23];
    float* out = (float*)d_out;
    (void)in_sizes; (void)n_in; (void)out_size; (void)ws_size;

    char* w = (char*)d_ws;
    unsigned short* hidden_bf = (unsigned short*)(w);                 // 16,777,216
    unsigned short* hio_pk    = (unsigned short*)(w + 16777216);      // 33,554,432
    unsigned short* inp_bf    = (unsigned short*)(w + 50331648);      // 33,554,432
    unsigned short* newh_bf   = (unsigned short*)(w + 83886080);      // 16,777,216
    unsigned short* Wio_pk    = (unsigned short*)(w + 100663296);     //    262,144
    unsigned short* Wi_pk     = (unsigned short*)(w + 100925440);     //    786,432
    unsigned short* Wh_pk     = (unsigned short*)(w + 101711872);     //    393,216
    unsigned short* W1pk      = (unsigned short*)(w + 102105088);     //    131,072
    unsigned short* W2pk      = (unsigned short*)(w + 102236160);     //    131,072
    unsigned short* Wn1pk     = (unsigned short*)(w + 102367232);     //    262,144
    unsigned short* Wn2pk     = (unsigned short*)(w + 102629376);     //    131,072
    unsigned short* ht_bf     = (unsigned short*)(w + 102760448);     //    262,144
    float*          q1buf     = (float*)         (w + 103022592);     //    524,288
    unsigned short* a_bf      = (unsigned short*)(w + 103546880);     //    262,144
    unsigned short* y_bf      = (unsigned short*)(w + 103809024);     //    262,144

    // weight packs
    pack_w<<<512,  256, 0, stream>>>(W_ein, W_eout, 256, 256, 512, 128, Wio_pk);
    pack_w<<<1536, 256, 0, stream>>>(W_i,   W_i,    768, 512, 768,  64, Wi_pk);
    pack_w<<<768,  256, 0, stream>>>(W_h,   W_h,    768, 256, 768,  64, Wh_pk);
    pack_w<<<256,  256, 0, stream>>>(W1,    W1,     256, 256, 256, 128, W1pk);
    pack_w<<<256,  256, 0, stream>>>(W2,    W2,     256, 256, 256, 256, W2pk);
    pack_w<<<512,  256, 0, stream>>>(Wn1,   Wn1,    256, 512, 256, 128, Wn1pk);
    pack_w<<<256,  256, 0, stream>>>(Wn2,   Wn2,    256, 256, 256, 128, Wn2pk);

    gather_emb   <<<4096, 256, 0, stream>>>(items, emb, hidden_bf);
    gemm_hio_mfma<<<dim3(256, 4), 256, 0, stream>>>(hidden_bf, Wio_pk, b_ein, b_eout, hio_pk);
    adj_mfma     <<<dim3(512, 2), 256, 0, stream>>>(A, hio_pk, b_iah, b_oah, inp_bf);
    gru_mfma     <<<dim3(256, 4), 256, 0, stream>>>(inp_bf, hidden_bf, Wi_pk, Wh_pk, b_i, b_h, newh_bf);
    prep_ht      <<<128, 256, 0, stream>>>(newh_bf, alias, mask, ht_bf);
    gemm_small<8,  false, false, false><<<dim3(4, 2), 256, 0, stream>>>(ht_bf, nullptr, W1pk, b1, q1buf, 2);
    attn_fused   <<<512, 256, 0, stream>>>(newh_bf, alias, mask, q1buf, b2, W3, W2pk, a_bf);
    gemm_small<16, true,  true,  true ><<<dim3(4, 2), 256, 0, stream>>>(a_bf, ht_bf, Wn1pk, bn1, y_bf, 2);
    gemm_small<8,  false, false, false><<<dim3(4, 2), 256, 0, stream>>>(y_bf, nullptr, Wn2pk, bn2, out, 2);
}

// Round 4
// 241.156 us; speedup vs baseline: 4.2624x; 1.0630x over previous
//
#include <hip/hip_runtime.h>
#include <hip/hip_bf16.h>
#include <math.h>

typedef short bhalf8 __attribute__((ext_vector_type(8)));
typedef float floatx4 __attribute__((ext_vector_type(4)));

__device__ __forceinline__ float sigmoidf_(float x) { return 1.0f / (1.0f + __expf(-x)); }

__device__ __forceinline__ unsigned short f2bf(float f) {
    unsigned int u = __builtin_bit_cast(unsigned int, f);
    u += 0x7FFFu + ((u >> 16) & 1u);
    return (unsigned short)(u >> 16);
}
__device__ __forceinline__ float bf2f(unsigned short h) {
    unsigned int u = ((unsigned int)h) << 16;
    return __builtin_bit_cast(float, u);
}

__device__ __forceinline__ floatx4 mfma16(bhalf8 a, bhalf8 b, floatx4 c) {
    return __builtin_amdgcn_mfma_f32_16x16x32_bf16(a, b, c, 0, 0, 0);
}

// async global->LDS, 16B per lane: LDS dest = uniform base + lane*16,
// global src is per-lane (pass src + lane*8 shorts).
__device__ __forceinline__ void gl_lds16(const unsigned short* g, unsigned short* l) {
    __builtin_amdgcn_global_load_lds(
        (const __attribute__((address_space(1))) void*)g,
        (__attribute__((address_space(3))) void*)l, 16, 0, 0);
}

// ---------------------------------------------------------------------------
// P0: pack weights f32 [K][N] -> bf16 B-fragment-linear tiles.
// t = ((kt*NT + nt)*FT + f)*512 + lane*8 + j
//   k = kt*32 + (lane>>4)*8 + j ; n = nt*BN + f*16 + (lane&15)
// ---------------------------------------------------------------------------
__global__ __launch_bounds__(256) void pack_w(
    const float* __restrict__ W0, const float* __restrict__ W1, int split,
    int K, int N, int BN, unsigned short* __restrict__ out)
{
    int t = blockIdx.x * 256 + threadIdx.x;
    int j = t & 7;
    int lane = (t >> 3) & 63;
    int FT = BN >> 4;
    int f = (t >> 9) % FT;
    int rest = t / (512 * FT);
    int NT = N / BN;
    int nt = rest % NT;
    int kt = rest / NT;
    int k = kt * 32 + (lane >> 4) * 8 + j;
    int n = nt * BN + f * 16 + (lane & 15);
    float v = (n < split) ? W0[(size_t)k * split + n]
                          : W1[(size_t)k * (N - split) + (n - split)];
    out[t] = f2bf(v);
}

// ---------------------------------------------------------------------------
// K1: hidden_pk = bf16(emb[items]) in A-fragment-packed layout:
// chunk i covers (m = (i>>9)*16 + (i&15... )): writes fully coalesced.
// layout(m,k) = (((m>>4)*8 + (k>>5))*64 + ((k>>3)&3)*16 + (m&15))*8 + (k&7)
// ---------------------------------------------------------------------------
__global__ __launch_bounds__(256) void gather_emb(
    const int* __restrict__ items, const float* __restrict__ emb,
    unsigned short* __restrict__ hidden_pk)
{
    int i = blockIdx.x * 256 + threadIdx.x;   // 1,048,576 chunks of 8
    int mg = i >> 9;
    int rem = i & 511;
    int l = rem & 63;
    int m = mg * 16 + (l & 15);
    int k = (rem >> 6) * 32 + (l >> 4) * 8;
    int it = items[m];
    const float* src = emb + (size_t)it * 256 + k;
    float4 v0 = *(const float4*)src;
    float4 v1 = *(const float4*)(src + 4);
    uint4 o;
    o.x = f2bf(v0.x) | ((unsigned)f2bf(v0.y) << 16);
    o.y = f2bf(v0.z) | ((unsigned)f2bf(v0.w) << 16);
    o.z = f2bf(v1.x) | ((unsigned)f2bf(v1.y) << 16);
    o.w = f2bf(v1.z) | ((unsigned)f2bf(v1.w) << 16);
    *(uint4*)(hidden_pk + (size_t)i * 8) = o;
}

// ---------------------------------------------------------------------------
// K2: hio = hidden @ [W_ein|W_eout] + bias -> packed for adj B-operand.
// Pure global_load_lds staging (A from hidden_pk, B from Wio_pk).
// ---------------------------------------------------------------------------
__global__ __launch_bounds__(256) void gemm_hio_mfma(
    const unsigned short* __restrict__ hidden_pk,
    const unsigned short* __restrict__ Wio_pk,
    const float* __restrict__ bein, const float* __restrict__ beout,
    unsigned short* __restrict__ hio_pk)
{
    __shared__ unsigned short As[4096];   // [8 rg][64 lane][8]
    __shared__ unsigned short Bs[4096];   // [8 f][64 lane][8]
    const int tid = threadIdx.x;
    const int wid = tid >> 6, lane = tid & 63;
    const int wr = wid >> 1, wc = wid & 1;
    const int bm = blockIdx.x * 128;
    const int nt = blockIdx.y;
    const int mg0 = bm >> 4;

    floatx4 acc[4][4] = {};
    for (int kt = 0; kt < 8; ++kt) {
        #pragma unroll
        for (int u = 0; u < 2; ++u) {
            int rg = wid * 2 + u;
            gl_lds16(hidden_pk + ((size_t)(mg0 + rg) * 8 + kt) * 512 + lane * 8, &As[rg * 512]);
            gl_lds16(Wio_pk + ((size_t)(kt * 4 + nt) * 8 + rg) * 512 + lane * 8, &Bs[rg * 512]);
        }
        __syncthreads();
        bhalf8 a[4], b[4];
        #pragma unroll
        for (int i = 0; i < 4; i++) a[i] = *(const bhalf8*)&As[(wr * 4 + i) * 512 + lane * 8];
        #pragma unroll
        for (int j = 0; j < 4; j++) b[j] = *(const bhalf8*)&Bs[(wc * 4 + j) * 512 + lane * 8];
        #pragma unroll
        for (int i = 0; i < 4; i++)
            #pragma unroll
            for (int j = 0; j < 4; j++) acc[i][j] = mfma16(a[i], b[j], acc[i][j]);
        __syncthreads();
    }
    const int r0 = (lane >> 4) * 4;
    #pragma unroll
    for (int mf = 0; mf < 4; mf++) {
        int m0 = bm + wr * 64 + mf * 16 + r0;
        int b_ = m0 >> 6;
        int ml = m0 & 63;
        int ktb = ml >> 5;
        int k0 = ml & 31;
        int j0 = k0 & 7;
        #pragma unroll
        for (int nf = 0; nf < 4; nf++) {
            int ng = nt * 128 + wc * 64 + nf * 16 + (lane & 15);
            int half = ng >> 8;
            int nh = ng & 255;
            float bias = half ? beout[nh] : bein[nh];
            int lane_b = ((k0 >> 3) << 4) + (nh & 15);
            size_t pb = ((((size_t)(b_ * 2 + half) * 2 + ktb) * 16 + (nh >> 4)) * 64 + lane_b) * 8 + j0;
            ushort4 o;
            o.x = f2bf(acc[mf][nf][0] + bias);
            o.y = f2bf(acc[mf][nf][1] + bias);
            o.z = f2bf(acc[mf][nf][2] + bias);
            o.w = f2bf(acc[mf][nf][3] + bias);
            *(ushort4*)(hio_pk + pb) = o;
        }
    }
}

// ---------------------------------------------------------------------------
// K3: inp = A_half @ hio_half + bias -> A-fragment-packed inp_pk (K=512).
// B staged via global_load_lds; A (f32->bf16) via reg route.
// ---------------------------------------------------------------------------
__global__ __launch_bounds__(256) void adj_mfma(
    const float* __restrict__ A,
    const unsigned short* __restrict__ hio_pk,
    const float* __restrict__ biah, const float* __restrict__ boah,
    unsigned short* __restrict__ inp_pk)
{
    __shared__ unsigned short As_[2048];   // [4 mf][64][8]
    __shared__ unsigned short Bs_[8192];   // [16 f][64][8]
    const int b = blockIdx.x;
    const int half = blockIdx.y;
    const int tid = threadIdx.x;
    const int wid = tid >> 6, lane = tid & 63;

    floatx4 acc[4][4] = {};
    for (int kt = 0; kt < 2; ++kt) {
        {   // stage adjacency (convert f32->bf16): 256 chunks of 8
            int r = tid >> 2, jj = tid & 3;
            const float* src = A + (size_t)b * 8192 + r * 128 + half * 64 + kt * 32 + jj * 8;
            float4 v0 = *(const float4*)src;
            float4 v1 = *(const float4*)(src + 4);
            uint4 o;
            o.x = f2bf(v0.x) | ((unsigned)f2bf(v0.y) << 16);
            o.y = f2bf(v0.z) | ((unsigned)f2bf(v0.w) << 16);
            o.z = f2bf(v1.x) | ((unsigned)f2bf(v1.y) << 16);
            o.w = f2bf(v1.z) | ((unsigned)f2bf(v1.w) << 16);
            *(uint4*)&As_[((r >> 4) * 64 + jj * 16 + (r & 15)) * 8] = o;
        }
        {   // stage B: 16 linear 1KB segments via global_load_lds
            const unsigned short* src = hio_pk + (size_t)((b * 2 + half) * 2 + kt) * 8192;
            #pragma unroll
            for (int u = 0; u < 4; ++u) {
                int sg = wid * 4 + u;
                gl_lds16(src + sg * 512 + lane * 8, &Bs_[sg * 512]);
            }
        }
        __syncthreads();
        bhalf8 a[4], bb[4];
        #pragma unroll
        for (int i = 0; i < 4; i++) a[i] = *(const bhalf8*)&As_[(i * 64 + lane) * 8];
        #pragma unroll
        for (int j = 0; j < 4; j++) bb[j] = *(const bhalf8*)&Bs_[((wid * 4 + j) * 64 + lane) * 8];
        #pragma unroll
        for (int i = 0; i < 4; i++)
            #pragma unroll
            for (int j = 0; j < 4; j++) acc[i][j] = mfma16(a[i], bb[j], acc[i][j]);
        __syncthreads();
    }
    const float* bias = half ? boah : biah;
    const int r0 = (lane >> 4) * 4;
    #pragma unroll
    for (int i = 0; i < 4; i++) {
        #pragma unroll
        for (int j = 0; j < 4; j++) {
            int nh = wid * 64 + j * 16 + (lane & 15);
            float bv = bias[nh];
            int kt5 = half * 8 + wid * 2 + (j >> 1);
            int l2 = ((j & 1) * 2 + ((lane >> 3) & 1)) * 16;
            #pragma unroll
            for (int reg = 0; reg < 4; reg++) {
                int mlo = r0 + reg;
                size_t dst = (((size_t)(b * 4 + i) * 16 + kt5) * 64 + l2 + mlo) * 8 + (lane & 7);
                inp_pk[dst] = f2bf(acc[i][j][reg] + bv);
            }
        }
    }
}

// ---------------------------------------------------------------------------
// K4: GRU cell, MFMA v2: BK=64 (12 stages), pure global_load_lds staging.
// Joint K over [inp_pk(16 kt) | hidden_pk(8 kt)]. Wave = 32 rows x 192 cols.
// ---------------------------------------------------------------------------
__global__ __launch_bounds__(256) void gru_mfma(
    const unsigned short* __restrict__ inp_pk,
    const unsigned short* __restrict__ hidden_pk,
    const unsigned short* __restrict__ Wi_pk,
    const unsigned short* __restrict__ Wh_pk,
    const float* __restrict__ bi, const float* __restrict__ bh,
    unsigned short* __restrict__ newh_bf)
{
    __shared__ unsigned short As2[2 * 8 * 512];    // [hh][rg][lane][8] = 16KB
    __shared__ unsigned short Bs2[2 * 3 * 4 * 512];// [hh][g][f][lane][8] = 24KB
    const int tid = threadIdx.x;
    const int wid = tid >> 6, lane = tid & 63;
    const int bm = blockIdx.x * 128;
    const int dt = blockIdx.y;
    const int mg0 = bm >> 4;

    floatx4 R[2][4] = {}, I[2][4] = {}, N0[2][4] = {}, N1[2][4] = {};

    for (int st = 0; st < 12; ++st) {
        const bool ph = st < 8;   // both kts of this stage in gi phase iff st<8
        // A: 16 segments of 1KB
        #pragma unroll
        for (int u = 0; u < 4; ++u) {
            int id = wid * 4 + u;
            int hh = id >> 3, rg = id & 7;
            int ktj = st * 2 + hh;
            const unsigned short* src = ph
                ? inp_pk    + ((size_t)(mg0 + rg) * 16 + ktj) * 512
                : hidden_pk + ((size_t)(mg0 + rg) * 8 + (ktj - 16)) * 512;
            gl_lds16(src + lane * 8, &As2[(hh * 8 + rg) * 512]);
        }
        // B: 24 segments of 1KB (2 halves x 3 gates x 4 f)
        const unsigned short* wb = ph ? Wi_pk : Wh_pk;
        #pragma unroll
        for (int u = 0; u < 6; ++u) {
            int id = wid * 6 + u;
            int hh = id / 12, v = id % 12;
            int g = v >> 2, q = v & 3;
            int ktj = st * 2 + hh;
            int ktl = ph ? ktj : ktj - 16;
            const unsigned short* src = wb + (size_t)(ktl * 12 + g * 4 + dt) * 2048 + q * 512;
            gl_lds16(src + lane * 8, &Bs2[((hh * 3 + g) * 4 + q) * 512]);
        }
        __syncthreads();
        #pragma unroll
        for (int hh = 0; hh < 2; ++hh) {
            bhalf8 a0 = *(const bhalf8*)&As2[(hh * 8 + wid * 2 + 0) * 512 + lane * 8];
            bhalf8 a1 = *(const bhalf8*)&As2[(hh * 8 + wid * 2 + 1) * 512 + lane * 8];
            #pragma unroll
            for (int j = 0; j < 4; ++j) {
                bhalf8 bv = *(const bhalf8*)&Bs2[((hh * 3 + 0) * 4 + j) * 512 + lane * 8];
                R[0][j] = mfma16(a0, bv, R[0][j]);
                R[1][j] = mfma16(a1, bv, R[1][j]);
            }
            #pragma unroll
            for (int j = 0; j < 4; ++j) {
                bhalf8 bv = *(const bhalf8*)&Bs2[((hh * 3 + 1) * 4 + j) * 512 + lane * 8];
                I[0][j] = mfma16(a0, bv, I[0][j]);
                I[1][j] = mfma16(a1, bv, I[1][j]);
            }
            if (ph) {
                #pragma unroll
                for (int j = 0; j < 4; ++j) {
                    bhalf8 bv = *(const bhalf8*)&Bs2[((hh * 3 + 2) * 4 + j) * 512 + lane * 8];
                    N0[0][j] = mfma16(a0, bv, N0[0][j]);
                    N0[1][j] = mfma16(a1, bv, N0[1][j]);
                }
            } else {
                #pragma unroll
                for (int j = 0; j < 4; ++j) {
                    bhalf8 bv = *(const bhalf8*)&Bs2[((hh * 3 + 2) * 4 + j) * 512 + lane * 8];
                    N1[0][j] = mfma16(a0, bv, N1[0][j]);
                    N1[1][j] = mfma16(a1, bv, N1[1][j]);
                }
            }
        }
        __syncthreads();
    }
    // Gates epilogue (hv from packed hidden)
    const int r0 = (lane >> 4) * 4;
    const int bd = dt * 64;
    #pragma unroll
    for (int i = 0; i < 2; i++) {
        #pragma unroll
        for (int j = 0; j < 4; j++) {
            int d = bd + j * 16 + (lane & 15);
            float bir = bi[d] + bh[d];
            float bii = bi[256 + d] + bh[256 + d];
            float bin = bi[512 + d];
            float bhn = bh[512 + d];
            #pragma unroll
            for (int reg = 0; reg < 4; reg++) {
                int m = bm + wid * 32 + i * 16 + r0 + reg;
                size_t hidx = (((size_t)(m >> 4) * 8 + (d >> 5)) * 64
                               + ((d >> 3) & 3) * 16 + (m & 15)) * 8 + (d & 7);
                float hv = bf2f(hidden_pk[hidx]);
                float rg = sigmoidf_(R[i][j][reg] + bir);
                float ig = sigmoidf_(I[i][j][reg] + bii);
                float ng = tanhf(N0[i][j][reg] + bin + rg * (N1[i][j][reg] + bhn));
                newh_bf[(size_t)m * 256 + d] = f2bf(ng + ig * (hv - ng));
            }
        }
    }
}

// ---------------------------------------------------------------------------
// K5: per-batch last index + ht gather (bf16). One wave per batch.
// ---------------------------------------------------------------------------
__global__ __launch_bounds__(256) void prep_ht(
    const unsigned short* __restrict__ newh_bf,
    const int* __restrict__ alias, const int* __restrict__ mask,
    unsigned short* __restrict__ ht_bf)
{
    int b = blockIdx.x * 4 + (threadIdx.x >> 6);
    int lane = threadIdx.x & 63;
    int mv = mask[b * 64 + lane];
    #pragma unroll
    for (int off = 32; off > 0; off >>= 1) mv += __shfl_xor(mv, off);
    int last = mv - 1;
    int node = alias[b * 64 + last];
    const unsigned short* src = newh_bf + (size_t)(b * 64 + node) * 256;
    unsigned short* dst = ht_bf + (size_t)b * 256;
    if (lane < 32) *(uint4*)(dst + lane * 8) = *(const uint4*)(src + lane * 8);
}

// ---------------------------------------------------------------------------
// K6: generic small MFMA GEMM, BM=128, BN=128, out stride 256.
// ---------------------------------------------------------------------------
template<int KT, bool CONCAT, bool RELU, bool OUTBF>
__global__ __launch_bounds__(256) void gemm_small(
    const unsigned short* __restrict__ A0, const unsigned short* __restrict__ A1,
    const unsigned short* __restrict__ Bpk, const float* __restrict__ bias,
    void* __restrict__ outp, int NT)
{
    __shared__ unsigned short As[4096];
    __shared__ unsigned short Bs[4096];
    const int tid = threadIdx.x;
    const int wid = tid >> 6, lane = tid & 63;
    const int wr = wid >> 1, wc = wid & 1;
    const int bm = blockIdx.x * 128, nt = blockIdx.y;

    floatx4 acc[4][4] = {};
    for (int kt = 0; kt < KT; ++kt) {
        #pragma unroll
        for (int it = 0; it < 2; ++it) {
            int s = tid + it * 256;
            int r = s >> 2, jj = s & 3;
            const unsigned short* src;
            if (CONCAT) {
                src = ((kt < 8) ? A0 : A1) + (size_t)(bm + r) * 256 + (kt & 7) * 32 + jj * 8;
            } else {
                src = A0 + (size_t)(bm + r) * 256 + kt * 32 + jj * 8;
            }
            *(uint4*)&As[((r >> 4) * 64 + jj * 16 + (r & 15)) * 8] = *(const uint4*)src;
            const unsigned short* bsrc = Bpk + ((size_t)(kt * NT + nt) * 8) * 512;
            *(uint4*)&Bs[s * 8] = *(const uint4*)(bsrc + s * 8);
        }
        __syncthreads();
        bhalf8 a[4], bb[4];
        #pragma unroll
        for (int i = 0; i < 4; i++) a[i] = *(const bhalf8*)&As[((wr * 4 + i) * 64 + lane) * 8];
        #pragma unroll
        for (int j = 0; j < 4; j++) bb[j] = *(const bhalf8*)&Bs[((wc * 4 + j) * 64 + lane) * 8];
        #pragma unroll
        for (int i = 0; i < 4; i++)
            #pragma unroll
            for (int j = 0; j < 4; j++) acc[i][j] = mfma16(a[i], bb[j], acc[i][j]);
        __syncthreads();
    }
    const int r0 = (lane >> 4) * 4;
    #pragma unroll
    for (int i = 0; i < 4; i++) {
        #pragma unroll
        for (int j = 0; j < 4; j++) {
            int col = nt * 128 + wc * 64 + j * 16 + (lane & 15);
            float bv = bias[col];
            #pragma unroll
            for (int reg = 0; reg < 4; reg++) {
                int m = bm + wr * 64 + i * 16 + r0 + reg;
                float v = acc[i][j][reg] + bv;
                if (RELU) v = fmaxf(v, 0.f);
                if (OUTBF) ((unsigned short*)outp)[(size_t)m * 256 + col] = f2bf(v);
                else       ((float*)outp)[(size_t)m * 256 + col] = v;
            }
        }
    }
}

// ---------------------------------------------------------------------------
// K7: fused attention. One block per batch.
// ---------------------------------------------------------------------------
__global__ __launch_bounds__(256) void attn_fused(
    const unsigned short* __restrict__ newh_bf,
    const int* __restrict__ alias, const int* __restrict__ mask,
    const float* __restrict__ q1, const float* __restrict__ b2,
    const float* __restrict__ W3,
    const unsigned short* __restrict__ W2pk,
    unsigned short* __restrict__ a_bf)
{
    const int b = blockIdx.x;
    const int tid = threadIdx.x;
    const int wid = tid >> 6, lane = tid & 63;
    __shared__ int arow[64];
    __shared__ float alphap[4][64];
    __shared__ float am[64];
    __shared__ unsigned short As[2048];
    __shared__ unsigned short Bs[8192];
    if (tid < 64) arow[tid] = b * 64 + alias[b * 64 + tid];
    __syncthreads();

    floatx4 acc[4][4] = {};
    for (int kt = 0; kt < 8; ++kt) {
        {
            int r = tid >> 2, jj = tid & 3;
            const unsigned short* src = newh_bf + (size_t)arow[r] * 256 + kt * 32 + jj * 8;
            *(uint4*)&As[((r >> 4) * 64 + jj * 16 + (r & 15)) * 8] = *(const uint4*)src;
        }
        {
            const unsigned short* src = W2pk + (size_t)kt * 16 * 512;
            #pragma unroll
            for (int u = 0; u < 4; ++u) {
                int sg = wid * 4 + u;
                gl_lds16(src + sg * 512 + lane * 8, &Bs[sg * 512]);
            }
        }
        __syncthreads();
        bhalf8 a[4], bb[4];
        #pragma unroll
        for (int i = 0; i < 4; i++) a[i] = *(const bhalf8*)&As[(i * 64 + lane) * 8];
        #pragma unroll
        for (int j = 0; j < 4; j++) bb[j] = *(const bhalf8*)&Bs[((wid * 4 + j) * 64 + lane) * 8];
        #pragma unroll
        for (int i = 0; i < 4; i++)
            #pragma unroll
            for (int j = 0; j < 4; j++) acc[i][j] = mfma16(a[i], bb[j], acc[i][j]);
        __syncthreads();
    }
    float q1v[4], b2v[4], w3v[4];
    #pragma unroll
    for (int j = 0; j < 4; j++) {
        int col = wid * 64 + j * 16 + (lane & 15);
        q1v[j] = q1[(size_t)b * 256 + col];
        b2v[j] = b2[col];
        w3v[j] = W3[col];
    }
    #pragma unroll
    for (int i = 0; i < 4; i++) {
        #pragma unroll
        for (int reg = 0; reg < 4; reg++) {
            float t = 0.f;
            #pragma unroll
            for (int j = 0; j < 4; j++)
                t += sigmoidf_(acc[i][j][reg] + q1v[j] + b2v[j]) * w3v[j];
            #pragma unroll
            for (int off = 1; off < 16; off <<= 1) t += __shfl_xor(t, off);
            if ((lane & 15) == 0) alphap[wid][i * 16 + (lane >> 4) * 4 + reg] = t;
        }
    }
    __syncthreads();
    if (tid < 64) {
        float al = alphap[0][tid] + alphap[1][tid] + alphap[2][tid] + alphap[3][tid];
        am[tid] = al * (float)mask[b * 64 + tid];
    }
    __syncthreads();
    float acca = 0.f;
    for (int l = 0; l < 64; ++l)
        acca = fmaf(am[l], bf2f(newh_bf[(size_t)arow[l] * 256 + tid]), acca);
    a_bf[(size_t)b * 256 + tid] = f2bf(acca);
}

// ---------------------------------------------------------------------------
extern "C" void kernel_launch(void* const* d_in, const int* in_sizes, int n_in,
                              void* d_out, int out_size, void* d_ws, size_t ws_size,
                              hipStream_t stream)
{
    const int*   alias  = (const int*)  d_in[0];
    const float* A      = (const float*)d_in[1];
    const int*   items  = (const int*)  d_in[2];
    const int*   mask   = (const int*)  d_in[3];
    const float* emb    = (const float*)d_in[4];
    const float* W_ein  = (const float*)d_in[5];
    const float* b_ein  = (const float*)d_in[6];
    const float* W_eout = (const float*)d_in[7];
    const float* b_eout = (const float*)d_in[8];
    const float* b_iah  = (const float*)d_in[9];
    const float* b_oah  = (const float*)d_in[10];
    const float* W_i    = (const float*)d_in[11];
    const float* b_i    = (const float*)d_in[12];
    const float* W_h    = (const float*)d_in[13];
    const float* b_h    = (const float*)d_in[14];
    const float* W1     = (const float*)d_in[15];
    const float* b1     = (const float*)d_in[16];
    const float* W2     = (const float*)d_in[17];
    const float* b2     = (const float*)d_in[18];
    const float* W3     = (const float*)d_in[19];
    const float* Wn1    = (const float*)d_in[20];
    const float* bn1    = (const float*)d_in[21];
    const float* Wn2    = (const float*)d_in[22];
    const float* bn2    = (const float*)d_in[23];
    float* out = (float*)d_out;
    (void)in_sizes; (void)n_in; (void)out_size; (void)ws_size;

    char* w = (char*)d_ws;
    unsigned short* hidden_pk = (unsigned short*)(w);                 // 16,777,216
    unsigned short* hio_pk    = (unsigned short*)(w + 16777216);      // 33,554,432
    unsigned short* inp_pk    = (unsigned short*)(w + 50331648);      // 33,554,432
    unsigned short* newh_bf   = (unsigned short*)(w + 83886080);      // 16,777,216
    unsigned short* Wio_pk    = (unsigned short*)(w + 100663296);     //    262,144
    unsigned short* Wi_pk     = (unsigned short*)(w + 100925440);     //    786,432
    unsigned short* Wh_pk     = (unsigned short*)(w + 101711872);     //    393,216
    unsigned short* W1pk      = (unsigned short*)(w + 102105088);     //    131,072
    unsigned short* W2pk      = (unsigned short*)(w + 102236160);     //    131,072
    unsigned short* Wn1pk     = (unsigned short*)(w + 102367232);     //    262,144
    unsigned short* Wn2pk     = (unsigned short*)(w + 102629376);     //    131,072
    unsigned short* ht_bf     = (unsigned short*)(w + 102760448);     //    262,144
    float*          q1buf     = (float*)         (w + 103022592);     //    524,288
    unsigned short* a_bf      = (unsigned short*)(w + 103546880);     //    262,144
    unsigned short* y_bf      = (unsigned short*)(w + 103809024);     //    262,144

    // weight packs (B-fragment-linear bf16)
    pack_w<<<512,  256, 0, stream>>>(W_ein, W_eout, 256, 256, 512, 128, Wio_pk);
    pack_w<<<1536, 256, 0, stream>>>(W_i,   W_i,    768, 512, 768,  64, Wi_pk);
    pack_w<<<768,  256, 0, stream>>>(W_h,   W_h,    768, 256, 768,  64, Wh_pk);
    pack_w<<<256,  256, 0, stream>>>(W1,    W1,     256, 256, 256, 128, W1pk);
    pack_w<<<256,  256, 0, stream>>>(W2,    W2,     256, 256, 256, 256, W2pk);
    pack_w<<<512,  256, 0, stream>>>(Wn1,   Wn1,    256, 512, 256, 128, Wn1pk);
    pack_w<<<256,  256, 0, stream>>>(Wn2,   Wn2,    256, 256, 256, 128, Wn2pk);

    gather_emb   <<<4096, 256, 0, stream>>>(items, emb, hidden_pk);
    gemm_hio_mfma<<<dim3(256, 4), 256, 0, stream>>>(hidden_pk, Wio_pk, b_ein, b_eout, hio_pk);
    adj_mfma     <<<dim3(512, 2), 256, 0, stream>>>(A, hio_pk, b_iah, b_oah, inp_pk);
    gru_mfma     <<<dim3(256, 4), 256, 0, stream>>>(inp_pk, hidden_pk, Wi_pk, Wh_pk, b_i, b_h, newh_bf);
    prep_ht      <<<128, 256, 0, stream>>>(newh_bf, alias, mask, ht_bf);
    gemm_small<8,  false, false, false><<<dim3(4, 2), 256, 0, stream>>>(ht_bf, nullptr, W1pk, b1, q1buf, 2);
    attn_fused   <<<512, 256, 0, stream>>>(newh_bf, alias, mask, q1buf, b2, W3, W2pk, a_bf);
    gemm_small<16, true,  true,  true ><<<dim3(4, 2), 256, 0, stream>>>(a_bf, ht_bf, Wn1pk, bn1, y_bf, 2);
    gemm_small<8,  false, false, false><<<dim3(4, 2), 256, 0, stream>>>(y_bf, nullptr, Wn2pk, bn2, out, 2);
}

// Round 5
// 193.607 us; speedup vs baseline: 5.3093x; 1.2456x over previous
//
#include <hip/hip_runtime.h>
#include <hip/hip_bf16.h>
#include <math.h>

typedef short bhalf8 __attribute__((ext_vector_type(8)));
typedef float floatx4 __attribute__((ext_vector_type(4)));

__device__ __forceinline__ float sigmoidf_(float x) { return 1.0f / (1.0f + __expf(-x)); }

__device__ __forceinline__ unsigned short f2bf(float f) {
    unsigned int u = __builtin_bit_cast(unsigned int, f);
    u += 0x7FFFu + ((u >> 16) & 1u);
    return (unsigned short)(u >> 16);
}
__device__ __forceinline__ float bf2f(unsigned short h) {
    unsigned int u = ((unsigned int)h) << 16;
    return __builtin_bit_cast(float, u);
}

__device__ __forceinline__ floatx4 mfma16(bhalf8 a, bhalf8 b, floatx4 c) {
    return __builtin_amdgcn_mfma_f32_16x16x32_bf16(a, b, c, 0, 0, 0);
}

// async global->LDS, 16B/lane: LDS dest = wave-uniform base + lane*16.
__device__ __forceinline__ void gl_lds16(const unsigned short* g, unsigned short* l) {
    __builtin_amdgcn_global_load_lds(
        (const __attribute__((address_space(1))) void*)g,
        (__attribute__((address_space(3))) void*)l, 16, 0, 0);
}

// ---------------------------------------------------------------------------
// P0: pack weights f32 [K][N] -> bf16 B-fragment-linear tiles.
// t = ((kt*NT + nt)*FT + f)*512 + lane*8 + j
//   k = kt*32 + (lane>>4)*8 + j ; n = nt*BN + f*16 + (lane&15)
// ---------------------------------------------------------------------------
__global__ __launch_bounds__(256) void pack_w(
    const float* __restrict__ W0, const float* __restrict__ W1, int split,
    int K, int N, int BN, unsigned short* __restrict__ out)
{
    int t = blockIdx.x * 256 + threadIdx.x;
    int j = t & 7;
    int lane = (t >> 3) & 63;
    int FT = BN >> 4;
    int f = (t >> 9) % FT;
    int rest = t / (512 * FT);
    int NT = N / BN;
    int nt = rest % NT;
    int kt = rest / NT;
    int k = kt * 32 + (lane >> 4) * 8 + j;
    int n = nt * BN + f * 16 + (lane & 15);
    float v = (n < split) ? W0[(size_t)k * split + n]
                          : W1[(size_t)k * (N - split) + (n - split)];
    out[t] = f2bf(v);
}

// ---------------------------------------------------------------------------
// P1: combined GRU weight pack: logical Wcat[768][768] = [W_i ; W_h].
// out[(((kt*4 + dt)*3 + g)*4 + f)*512 + lane*8 + j]
//   k = kt*32 + (lane>>4)*8 + j ; n = g*256 + dt*64 + f*16 + (lane&15)
// ---------------------------------------------------------------------------
__global__ __launch_bounds__(256) void pack_w_gru(
    const float* __restrict__ Wi, const float* __restrict__ Wh,
    unsigned short* __restrict__ out)
{
    int t = blockIdx.x * 256 + threadIdx.x;   // 589,824 total
    int j = t & 7;
    int lane = (t >> 3) & 63;
    int f = (t >> 9) & 3;
    int q = t >> 11;
    int g = q % 3;
    int p = q / 3;
    int dt = p & 3;
    int kt = p >> 2;
    int k = kt * 32 + (lane >> 4) * 8 + j;
    int n = g * 256 + dt * 64 + f * 16 + (lane & 15);
    float v = (k < 512) ? Wi[(size_t)k * 768 + n] : Wh[(size_t)(k - 512) * 768 + n];
    out[t] = f2bf(v);
}

// ---------------------------------------------------------------------------
// K1: hidden_pk = bf16(emb[items]) in A-fragment-packed layout.
// layout(m,k) = (((m>>4)*8 + (k>>5))*64 + ((k>>3)&3)*16 + (m&15))*8 + (k&7)
// ---------------------------------------------------------------------------
__global__ __launch_bounds__(256) void gather_emb(
    const int* __restrict__ items, const float* __restrict__ emb,
    unsigned short* __restrict__ hidden_pk)
{
    int i = blockIdx.x * 256 + threadIdx.x;   // 1,048,576 chunks of 8
    int mg = i >> 9;
    int rem = i & 511;
    int l = rem & 63;
    int m = mg * 16 + (l & 15);
    int k = (rem >> 6) * 32 + (l >> 4) * 8;
    int it = items[m];
    const float* src = emb + (size_t)it * 256 + k;
    float4 v0 = *(const float4*)src;
    float4 v1 = *(const float4*)(src + 4);
    uint4 o;
    o.x = f2bf(v0.x) | ((unsigned)f2bf(v0.y) << 16);
    o.y = f2bf(v0.z) | ((unsigned)f2bf(v0.w) << 16);
    o.z = f2bf(v1.x) | ((unsigned)f2bf(v1.y) << 16);
    o.w = f2bf(v1.z) | ((unsigned)f2bf(v1.w) << 16);
    *(uint4*)(hidden_pk + (size_t)i * 8) = o;
}

// ---------------------------------------------------------------------------
// K2: hio = hidden @ [W_ein|W_eout] + bias -> packed for adj B-operand.
// 2-phase double-buffered global_load_lds staging.
// ---------------------------------------------------------------------------
__global__ __launch_bounds__(256) void gemm_hio_mfma(
    const unsigned short* __restrict__ hidden_pk,
    const unsigned short* __restrict__ Wio_pk,
    const float* __restrict__ bein, const float* __restrict__ beout,
    unsigned short* __restrict__ hio_pk)
{
    __shared__ unsigned short As[2][4096];
    __shared__ unsigned short Bs[2][4096];
    const int tid = threadIdx.x;
    const int wid = tid >> 6, lane = tid & 63;
    const int wr = wid >> 1, wc = wid & 1;
    const int bm = blockIdx.x * 128;
    const int nt = blockIdx.y;
    const int mg0 = bm >> 4;

    auto stage = [&](int kt, int buf) {
        #pragma unroll
        for (int u = 0; u < 2; ++u) {
            int rg = wid * 2 + u;
            gl_lds16(hidden_pk + ((size_t)(mg0 + rg) * 8 + kt) * 512 + lane * 8, &As[buf][rg * 512]);
            gl_lds16(Wio_pk + ((size_t)(kt * 4 + nt) * 8 + rg) * 512 + lane * 8, &Bs[buf][rg * 512]);
        }
    };

    floatx4 acc[4][4] = {};
    stage(0, 0);
    __syncthreads();
    for (int kt = 0; kt < 8; ++kt) {
        int cur = kt & 1;
        if (kt < 7) stage(kt + 1, cur ^ 1);
        bhalf8 a[4], b[4];
        #pragma unroll
        for (int i = 0; i < 4; i++) a[i] = *(const bhalf8*)&As[cur][(wr * 4 + i) * 512 + lane * 8];
        #pragma unroll
        for (int j = 0; j < 4; j++) b[j] = *(const bhalf8*)&Bs[cur][(wc * 4 + j) * 512 + lane * 8];
        #pragma unroll
        for (int i = 0; i < 4; i++)
            #pragma unroll
            for (int j = 0; j < 4; j++) acc[i][j] = mfma16(a[i], b[j], acc[i][j]);
        __syncthreads();
    }
    const int r0 = (lane >> 4) * 4;
    #pragma unroll
    for (int mf = 0; mf < 4; mf++) {
        int m0 = bm + wr * 64 + mf * 16 + r0;
        int b_ = m0 >> 6;
        int ml = m0 & 63;
        int ktb = ml >> 5;
        int k0 = ml & 31;
        int j0 = k0 & 7;
        #pragma unroll
        for (int nf = 0; nf < 4; nf++) {
            int ng = nt * 128 + wc * 64 + nf * 16 + (lane & 15);
            int half = ng >> 8;
            int nh = ng & 255;
            float bias = half ? beout[nh] : bein[nh];
            int lane_b = ((k0 >> 3) << 4) + (nh & 15);
            size_t pb = ((((size_t)(b_ * 2 + half) * 2 + ktb) * 16 + (nh >> 4)) * 64 + lane_b) * 8 + j0;
            ushort4 o;
            o.x = f2bf(acc[mf][nf][0] + bias);
            o.y = f2bf(acc[mf][nf][1] + bias);
            o.z = f2bf(acc[mf][nf][2] + bias);
            o.w = f2bf(acc[mf][nf][3] + bias);
            *(ushort4*)(hio_pk + pb) = o;
        }
    }
}

// ---------------------------------------------------------------------------
// K3: inp = A_half @ hio_half + bias -> A-fragment-packed inp_pk (K=512).
// ---------------------------------------------------------------------------
__global__ __launch_bounds__(256) void adj_mfma(
    const float* __restrict__ A,
    const unsigned short* __restrict__ hio_pk,
    const float* __restrict__ biah, const float* __restrict__ boah,
    unsigned short* __restrict__ inp_pk)
{
    __shared__ unsigned short As_[2048];
    __shared__ unsigned short Bs_[8192];
    const int b = blockIdx.x;
    const int half = blockIdx.y;
    const int tid = threadIdx.x;
    const int wid = tid >> 6, lane = tid & 63;

    floatx4 acc[4][4] = {};
    for (int kt = 0; kt < 2; ++kt) {
        {
            int r = tid >> 2, jj = tid & 3;
            const float* src = A + (size_t)b * 8192 + r * 128 + half * 64 + kt * 32 + jj * 8;
            float4 v0 = *(const float4*)src;
            float4 v1 = *(const float4*)(src + 4);
            uint4 o;
            o.x = f2bf(v0.x) | ((unsigned)f2bf(v0.y) << 16);
            o.y = f2bf(v0.z) | ((unsigned)f2bf(v0.w) << 16);
            o.z = f2bf(v1.x) | ((unsigned)f2bf(v1.y) << 16);
            o.w = f2bf(v1.z) | ((unsigned)f2bf(v1.w) << 16);
            *(uint4*)&As_[((r >> 4) * 64 + jj * 16 + (r & 15)) * 8] = o;
        }
        {
            const unsigned short* src = hio_pk + (size_t)((b * 2 + half) * 2 + kt) * 8192;
            #pragma unroll
            for (int u = 0; u < 4; ++u) {
                int sg = wid * 4 + u;
                gl_lds16(src + sg * 512 + lane * 8, &Bs_[sg * 512]);
            }
        }
        __syncthreads();
        bhalf8 a[4], bb[4];
        #pragma unroll
        for (int i = 0; i < 4; i++) a[i] = *(const bhalf8*)&As_[(i * 64 + lane) * 8];
        #pragma unroll
        for (int j = 0; j < 4; j++) bb[j] = *(const bhalf8*)&Bs_[((wid * 4 + j) * 64 + lane) * 8];
        #pragma unroll
        for (int i = 0; i < 4; i++)
            #pragma unroll
            for (int j = 0; j < 4; j++) acc[i][j] = mfma16(a[i], bb[j], acc[i][j]);
        __syncthreads();
    }
    const float* bias = half ? boah : biah;
    const int r0 = (lane >> 4) * 4;
    #pragma unroll
    for (int i = 0; i < 4; i++) {
        #pragma unroll
        for (int j = 0; j < 4; j++) {
            int nh = wid * 64 + j * 16 + (lane & 15);
            float bv = bias[nh];
            int kt5 = half * 8 + wid * 2 + (j >> 1);
            int l2 = ((j & 1) * 2 + ((lane >> 3) & 1)) * 16;
            #pragma unroll
            for (int reg = 0; reg < 4; reg++) {
                int mlo = r0 + reg;
                size_t dst = (((size_t)(b * 4 + i) * 16 + kt5) * 64 + l2 + mlo) * 8 + (lane & 7);
                inp_pk[dst] = f2bf(acc[i][j][reg] + bv);
            }
        }
    }
}

// ---------------------------------------------------------------------------
// K4: GRU cell v3: BK=32, 24 uniform stages over combined Wg_pk (K=768),
// 2-phase double-buffered global_load_lds staging.
// ---------------------------------------------------------------------------
__global__ __launch_bounds__(256) void gru_mfma(
    const unsigned short* __restrict__ inp_pk,
    const unsigned short* __restrict__ hidden_pk,
    const unsigned short* __restrict__ Wg_pk,
    const float* __restrict__ bi, const float* __restrict__ bh,
    unsigned short* __restrict__ newh_bf)
{
    __shared__ unsigned short As2[2][4096];    // 8KB per buf
    __shared__ unsigned short Bs2[2][6144];    // 12KB per buf
    const int tid = threadIdx.x;
    const int wid = tid >> 6, lane = tid & 63;
    const int bm = blockIdx.x * 128;
    const int dt = blockIdx.y;
    const int mg0 = bm >> 4;

    floatx4 R[2][4] = {}, I[2][4] = {}, N0[2][4] = {}, N1[2][4] = {};

    auto stage = [&](int st, int buf) {
        #pragma unroll
        for (int u = 0; u < 2; ++u) {
            int rg = wid * 2 + u;
            const unsigned short* src = (st < 16)
                ? inp_pk    + ((size_t)(mg0 + rg) * 16 + st) * 512
                : hidden_pk + ((size_t)(mg0 + rg) * 8 + (st - 16)) * 512;
            gl_lds16(src + lane * 8, &As2[buf][rg * 512]);
        }
        #pragma unroll
        for (int u = 0; u < 3; ++u) {
            int sg = wid * 3 + u;
            gl_lds16(Wg_pk + ((size_t)(st * 4 + dt) * 12 + sg) * 512 + lane * 8, &Bs2[buf][sg * 512]);
        }
    };

    stage(0, 0);
    __syncthreads();
    for (int st = 0; st < 24; ++st) {
        int cur = st & 1;
        if (st < 23) stage(st + 1, cur ^ 1);
        bhalf8 a0 = *(const bhalf8*)&As2[cur][(wid * 2 + 0) * 512 + lane * 8];
        bhalf8 a1 = *(const bhalf8*)&As2[cur][(wid * 2 + 1) * 512 + lane * 8];
        #pragma unroll
        for (int j = 0; j < 4; ++j) {
            bhalf8 bv = *(const bhalf8*)&Bs2[cur][(0 * 4 + j) * 512 + lane * 8];
            R[0][j] = mfma16(a0, bv, R[0][j]);
            R[1][j] = mfma16(a1, bv, R[1][j]);
        }
        #pragma unroll
        for (int j = 0; j < 4; ++j) {
            bhalf8 bv = *(const bhalf8*)&Bs2[cur][(1 * 4 + j) * 512 + lane * 8];
            I[0][j] = mfma16(a0, bv, I[0][j]);
            I[1][j] = mfma16(a1, bv, I[1][j]);
        }
        if (st < 16) {
            #pragma unroll
            for (int j = 0; j < 4; ++j) {
                bhalf8 bv = *(const bhalf8*)&Bs2[cur][(2 * 4 + j) * 512 + lane * 8];
                N0[0][j] = mfma16(a0, bv, N0[0][j]);
                N0[1][j] = mfma16(a1, bv, N0[1][j]);
            }
        } else {
            #pragma unroll
            for (int j = 0; j < 4; ++j) {
                bhalf8 bv = *(const bhalf8*)&Bs2[cur][(2 * 4 + j) * 512 + lane * 8];
                N1[0][j] = mfma16(a0, bv, N1[0][j]);
                N1[1][j] = mfma16(a1, bv, N1[1][j]);
            }
        }
        __syncthreads();
    }
    // Gates epilogue (hv from packed hidden)
    const int r0 = (lane >> 4) * 4;
    const int bd = dt * 64;
    #pragma unroll
    for (int i = 0; i < 2; i++) {
        #pragma unroll
        for (int j = 0; j < 4; j++) {
            int d = bd + j * 16 + (lane & 15);
            float bir = bi[d] + bh[d];
            float bii = bi[256 + d] + bh[256 + d];
            float bin = bi[512 + d];
            float bhn = bh[512 + d];
            #pragma unroll
            for (int reg = 0; reg < 4; reg++) {
                int m = bm + wid * 32 + i * 16 + r0 + reg;
                size_t hidx = (((size_t)(m >> 4) * 8 + (d >> 5)) * 64
                               + ((d >> 3) & 3) * 16 + (m & 15)) * 8 + (d & 7);
                float hv = bf2f(hidden_pk[hidx]);
                float rg = sigmoidf_(R[i][j][reg] + bir);
                float ig = sigmoidf_(I[i][j][reg] + bii);
                float ng = tanhf(N0[i][j][reg] + bin + rg * (N1[i][j][reg] + bhn));
                newh_bf[(size_t)m * 256 + d] = f2bf(ng + ig * (hv - ng));
            }
        }
    }
}

// ---------------------------------------------------------------------------
// K5: per-batch last index + ht gather (bf16). One wave per batch.
// ---------------------------------------------------------------------------
__global__ __launch_bounds__(256) void prep_ht(
    const unsigned short* __restrict__ newh_bf,
    const int* __restrict__ alias, const int* __restrict__ mask,
    unsigned short* __restrict__ ht_bf)
{
    int b = blockIdx.x * 4 + (threadIdx.x >> 6);
    int lane = threadIdx.x & 63;
    int mv = mask[b * 64 + lane];
    #pragma unroll
    for (int off = 32; off > 0; off >>= 1) mv += __shfl_xor(mv, off);
    int last = mv - 1;
    int node = alias[b * 64 + last];
    const unsigned short* src = newh_bf + (size_t)(b * 64 + node) * 256;
    unsigned short* dst = ht_bf + (size_t)b * 256;
    if (lane < 32) *(uint4*)(dst + lane * 8) = *(const uint4*)(src + lane * 8);
}

// ---------------------------------------------------------------------------
// K6: generic small MFMA GEMM, BM=128, BN=128, out stride 256.
// ---------------------------------------------------------------------------
template<int KT, bool CONCAT, bool RELU, bool OUTBF>
__global__ __launch_bounds__(256) void gemm_small(
    const unsigned short* __restrict__ A0, const unsigned short* __restrict__ A1,
    const unsigned short* __restrict__ Bpk, const float* __restrict__ bias,
    void* __restrict__ outp, int NT)
{
    __shared__ unsigned short As[4096];
    __shared__ unsigned short Bs[4096];
    const int tid = threadIdx.x;
    const int wid = tid >> 6, lane = tid & 63;
    const int wr = wid >> 1, wc = wid & 1;
    const int bm = blockIdx.x * 128, nt = blockIdx.y;

    floatx4 acc[4][4] = {};
    for (int kt = 0; kt < KT; ++kt) {
        #pragma unroll
        for (int it = 0; it < 2; ++it) {
            int s = tid + it * 256;
            int r = s >> 2, jj = s & 3;
            const unsigned short* src;
            if (CONCAT) {
                src = ((kt < 8) ? A0 : A1) + (size_t)(bm + r) * 256 + (kt & 7) * 32 + jj * 8;
            } else {
                src = A0 + (size_t)(bm + r) * 256 + kt * 32 + jj * 8;
            }
            *(uint4*)&As[((r >> 4) * 64 + jj * 16 + (r & 15)) * 8] = *(const uint4*)src;
            const unsigned short* bsrc = Bpk + ((size_t)(kt * NT + nt) * 8) * 512;
            *(uint4*)&Bs[s * 8] = *(const uint4*)(bsrc + s * 8);
        }
        __syncthreads();
        bhalf8 a[4], bb[4];
        #pragma unroll
        for (int i = 0; i < 4; i++) a[i] = *(const bhalf8*)&As[((wr * 4 + i) * 64 + lane) * 8];
        #pragma unroll
        for (int j = 0; j < 4; j++) bb[j] = *(const bhalf8*)&Bs[((wc * 4 + j) * 64 + lane) * 8];
        #pragma unroll
        for (int i = 0; i < 4; i++)
            #pragma unroll
            for (int j = 0; j < 4; j++) acc[i][j] = mfma16(a[i], bb[j], acc[i][j]);
        __syncthreads();
    }
    const int r0 = (lane >> 4) * 4;
    #pragma unroll
    for (int i = 0; i < 4; i++) {
        #pragma unroll
        for (int j = 0; j < 4; j++) {
            int col = nt * 128 + wc * 64 + j * 16 + (lane & 15);
            float bv = bias[col];
            #pragma unroll
            for (int reg = 0; reg < 4; reg++) {
                int m = bm + wr * 64 + i * 16 + r0 + reg;
                float v = acc[i][j][reg] + bv;
                if (RELU) v = fmaxf(v, 0.f);
                if (OUTBF) ((unsigned short*)outp)[(size_t)m * 256 + col] = f2bf(v);
                else       ((float*)outp)[(size_t)m * 256 + col] = v;
            }
        }
    }
}

// ---------------------------------------------------------------------------
// K7: fused attention. One block per batch.
// ---------------------------------------------------------------------------
__global__ __launch_bounds__(256) void attn_fused(
    const unsigned short* __restrict__ newh_bf,
    const int* __restrict__ alias, const int* __restrict__ mask,
    const float* __restrict__ q1, const float* __restrict__ b2,
    const float* __restrict__ W3,
    const unsigned short* __restrict__ W2pk,
    unsigned short* __restrict__ a_bf)
{
    const int b = blockIdx.x;
    const int tid = threadIdx.x;
    const int wid = tid >> 6, lane = tid & 63;
    __shared__ int arow[64];
    __shared__ float alphap[4][64];
    __shared__ float am[64];
    __shared__ unsigned short As[2048];
    __shared__ unsigned short Bs[8192];
    if (tid < 64) arow[tid] = b * 64 + alias[b * 64 + tid];
    __syncthreads();

    floatx4 acc[4][4] = {};
    for (int kt = 0; kt < 8; ++kt) {
        {
            int r = tid >> 2, jj = tid & 3;
            const unsigned short* src = newh_bf + (size_t)arow[r] * 256 + kt * 32 + jj * 8;
            *(uint4*)&As[((r >> 4) * 64 + jj * 16 + (r & 15)) * 8] = *(const uint4*)src;
        }
        {
            const unsigned short* src = W2pk + (size_t)kt * 16 * 512;
            #pragma unroll
            for (int u = 0; u < 4; ++u) {
                int sg = wid * 4 + u;
                gl_lds16(src + sg * 512 + lane * 8, &Bs[sg * 512]);
            }
        }
        __syncthreads();
        bhalf8 a[4], bb[4];
        #pragma unroll
        for (int i = 0; i < 4; i++) a[i] = *(const bhalf8*)&As[(i * 64 + lane) * 8];
        #pragma unroll
        for (int j = 0; j < 4; j++) bb[j] = *(const bhalf8*)&Bs[((wid * 4 + j) * 64 + lane) * 8];
        #pragma unroll
        for (int i = 0; i < 4; i++)
            #pragma unroll
            for (int j = 0; j < 4; j++) acc[i][j] = mfma16(a[i], bb[j], acc[i][j]);
        __syncthreads();
    }
    float q1v[4], b2v[4], w3v[4];
    #pragma unroll
    for (int j = 0; j < 4; j++) {
        int col = wid * 64 + j * 16 + (lane & 15);
        q1v[j] = q1[(size_t)b * 256 + col];
        b2v[j] = b2[col];
        w3v[j] = W3[col];
    }
    #pragma unroll
    for (int i = 0; i < 4; i++) {
        #pragma unroll
        for (int reg = 0; reg < 4; reg++) {
            float t = 0.f;
            #pragma unroll
            for (int j = 0; j < 4; j++)
                t += sigmoidf_(acc[i][j][reg] + q1v[j] + b2v[j]) * w3v[j];
            #pragma unroll
            for (int off = 1; off < 16; off <<= 1) t += __shfl_xor(t, off);
            if ((lane & 15) == 0) alphap[wid][i * 16 + (lane >> 4) * 4 + reg] = t;
        }
    }
    __syncthreads();
    if (tid < 64) {
        float al = alphap[0][tid] + alphap[1][tid] + alphap[2][tid] + alphap[3][tid];
        am[tid] = al * (float)mask[b * 64 + tid];
    }
    __syncthreads();
    float acca = 0.f;
    for (int l = 0; l < 64; ++l)
        acca = fmaf(am[l], bf2f(newh_bf[(size_t)arow[l] * 256 + tid]), acca);
    a_bf[(size_t)b * 256 + tid] = f2bf(acca);
}

// ---------------------------------------------------------------------------
extern "C" void kernel_launch(void* const* d_in, const int* in_sizes, int n_in,
                              void* d_out, int out_size, void* d_ws, size_t ws_size,
                              hipStream_t stream)
{
    const int*   alias  = (const int*)  d_in[0];
    const float* A      = (const float*)d_in[1];
    const int*   items  = (const int*)  d_in[2];
    const int*   mask   = (const int*)  d_in[3];
    const float* emb    = (const float*)d_in[4];
    const float* W_ein  = (const float*)d_in[5];
    const float* b_ein  = (const float*)d_in[6];
    const float* W_eout = (const float*)d_in[7];
    const float* b_eout = (const float*)d_in[8];
    const float* b_iah  = (const float*)d_in[9];
    const float* b_oah  = (const float*)d_in[10];
    const float* W_i    = (const float*)d_in[11];
    const float* b_i    = (const float*)d_in[12];
    const float* W_h    = (const float*)d_in[13];
    const float* b_h    = (const float*)d_in[14];
    const float* W1     = (const float*)d_in[15];
    const float* b1     = (const float*)d_in[16];
    const float* W2     = (const float*)d_in[17];
    const float* b2     = (const float*)d_in[18];
    const float* W3     = (const float*)d_in[19];
    const float* Wn1    = (const float*)d_in[20];
    const float* bn1    = (const float*)d_in[21];
    const float* Wn2    = (const float*)d_in[22];
    const float* bn2    = (const float*)d_in[23];
    float* out = (float*)d_out;
    (void)in_sizes; (void)n_in; (void)out_size; (void)ws_size;

    char* w = (char*)d_ws;
    unsigned short* hidden_pk = (unsigned short*)(w);                 // 16,777,216
    unsigned short* hio_pk    = (unsigned short*)(w + 16777216);      // 33,554,432
    unsigned short* inp_pk    = (unsigned short*)(w + 50331648);      // 33,554,432
    unsigned short* newh_bf   = (unsigned short*)(w + 83886080);      // 16,777,216
    unsigned short* Wio_pk    = (unsigned short*)(w + 100663296);     //    262,144
    unsigned short* Wg_pk     = (unsigned short*)(w + 100925440);     //  1,179,648
    unsigned short* W1pk      = (unsigned short*)(w + 102105088);     //    131,072
    unsigned short* W2pk      = (unsigned short*)(w + 102236160);     //    131,072
    unsigned short* Wn1pk     = (unsigned short*)(w + 102367232);     //    262,144
    unsigned short* Wn2pk     = (unsigned short*)(w + 102629376);     //    131,072
    unsigned short* ht_bf     = (unsigned short*)(w + 102760448);     //    262,144
    float*          q1buf     = (float*)         (w + 103022592);     //    524,288
    unsigned short* a_bf      = (unsigned short*)(w + 103546880);     //    262,144
    unsigned short* y_bf      = (unsigned short*)(w + 103809024);     //    262,144

    // weight packs (bf16, fragment-linear)
    pack_w    <<<512,  256, 0, stream>>>(W_ein, W_eout, 256, 256, 512, 128, Wio_pk);
    pack_w_gru<<<2304, 256, 0, stream>>>(W_i, W_h, Wg_pk);
    pack_w    <<<256,  256, 0, stream>>>(W1,  W1,  256, 256, 256, 128, W1pk);
    pack_w    <<<256,  256, 0, stream>>>(W2,  W2,  256, 256, 256, 256, W2pk);
    pack_w    <<<512,  256, 0, stream>>>(Wn1, Wn1, 256, 512, 256, 128, Wn1pk);
    pack_w    <<<256,  256, 0, stream>>>(Wn2, Wn2, 256, 256, 256, 128, Wn2pk);

    gather_emb   <<<4096, 256, 0, stream>>>(items, emb, hidden_pk);
    gemm_hio_mfma<<<dim3(256, 4), 256, 0, stream>>>(hidden_pk, Wio_pk, b_ein, b_eout, hio_pk);
    adj_mfma     <<<dim3(512, 2), 256, 0, stream>>>(A, hio_pk, b_iah, b_oah, inp_pk);
    gru_mfma     <<<dim3(256, 4), 256, 0, stream>>>(inp_pk, hidden_pk, Wg_pk, b_i, b_h, newh_bf);
    prep_ht      <<<128, 256, 0, stream>>>(newh_bf, alias, mask, ht_bf);
    gemm_small<8,  false, false, false><<<dim3(4, 2), 256, 0, stream>>>(ht_bf, nullptr, W1pk, b1, q1buf, 2);
    attn_fused   <<<512, 256, 0, stream>>>(newh_bf, alias, mask, q1buf, b2, W3, W2pk, a_bf);
    gemm_small<16, true,  true,  true ><<<dim3(4, 2), 256, 0, stream>>>(a_bf, ht_bf, Wn1pk, bn1, y_bf, 2);
    gemm_small<8,  false, false, false><<<dim3(4, 2), 256, 0, stream>>>(y_bf, nullptr, Wn2pk, bn2, out, 2);
}